// Round 2
// baseline (8773.765 us; speedup 1.0000x reference)
//
#include <hip/hip_runtime.h>
#include <hip/hip_bf16.h>

#define NB   2048
#define NN0  111
#define NN1  56
#define NN2  28
#define FD   256
#define HD   128
#define SX1  129   // stage1 xsT col stride (odd -> conflict-free scatter/reads)
#define SP1  66    // stage1 P-buffer stride (even, b64-aligned pairs, 2-way banks)
#define SX2  65    // stage2 hT col stride
#define SP2  66

// ---------------------------------------------------------------------------
// K1: stage-1 conv. One block/graph, 512 thr.
// xsT[k][i] transposed in LDS; weight GEMM: per-lane x reads + uniform W loads;
// props: dis-prescaled P buffers, float2 neighbor adds via adjacency bitmask.
// ---------------------------------------------------------------------------
__global__ __launch_bounds__(512) void k_stage1(
    const float* __restrict__ x, const float* __restrict__ adj,
    const float* __restrict__ wg, const float* __restrict__ wsp,
    float* __restrict__ h1, int b0)
{
  extern __shared__ float sm[];
  float* xsT  = sm;                               // 111*129
  float* bufA = xsT + NN0 * SX1;                  // 111*66
  float* bufB = bufA + NN0 * SP1;                 // 111*66
  float* bufC = bufB + NN0 * SP1;                 // 111*66
  unsigned* abits = (unsigned*)(bufC + NN0 * SP1);// 444 (+pad)
  float* dis0 = (float*)(abits + 448);            // 112
  float* dis1 = dis0 + 112;                       // 112

  const int tid  = threadIdx.x;
  const int lane = tid & 63;
  const int wv   = tid >> 6;
  const int b    = b0 + blockIdx.x;
  const float* xb = x   + (size_t)b * (NN0 * NN0);
  const float* ab = adj + (size_t)b * (NN0 * NN0);

  for (int q = tid; q < NN0 * SX1; q += 512) xsT[q] = 0.0f;
  __syncthreads();
  for (int idx = tid; idx < NN0 * NN0; idx += 512) {
    int i = idx / NN0, k = idx - i * NN0;
    xsT[k * SX1 + i] = xb[idx];
  }
  for (int i = wv; i < NN0; i += 8) {
    unsigned long long m0 = __ballot(ab[i * NN0 + lane] != 0.0f);
    float a1v = (64 + lane < NN0) ? ab[i * NN0 + 64 + lane] : 0.0f;
    unsigned long long m1 = __ballot(a1v != 0.0f);
    if (lane == 0) {
      abits[i * 4 + 0] = (unsigned)m0; abits[i * 4 + 1] = (unsigned)(m0 >> 32);
      abits[i * 4 + 2] = (unsigned)m1; abits[i * 4 + 3] = (unsigned)(m1 >> 32);
      int d = __popcll(m0) + __popcll(m1);
      dis0[i] = (d > 0) ? (1.0f / sqrtf((float)d)) : 0.0f;
      dis1[i] = 1.0f / sqrtf((float)(d + 1));
    }
  }
  __syncthreads();

  const int cgu = __builtin_amdgcn_readfirstlane(wv & 3);   // col group 0..3
  const int rhu = __builtin_amdgcn_readfirstlane(wv >> 2);  // row half 0..1
  const int row = rhu * 64 + lane;                          // 0..127 (pad >=111)
  const int prg = tid >> 5;                                 // 0..15
  const int pcp = tid & 31;                                 // col pair
  float* h1b = h1 + (size_t)blockIdx.x * (NN0 * FD);

  auto nsum2 = [&](int i, const float* buf) {
    float2 acc = make_float2(0.f, 0.f);
    const unsigned* rb = abits + i * 4;
#pragma unroll
    for (int w = 0; w < 4; ++w) {
      unsigned u = rb[w];
      while (u) {
        int j = (w << 5) + __builtin_ctz(u); u &= u - 1;
        float2 p = *(const float2*)&buf[j * SP1 + 2 * pcp];
        acc.x += p.x; acc.y += p.y;
      }
    }
    return acc;
  };

  for (int c = 0; c < 2; ++c) {
    const int c0 = c * 64;
    // ---- sweep 1: Pg (wg) -> bufA(dis1-scaled); P2 (wsp[2]) -> bufB(dis0-scaled), bufC(raw)
    {
      float ag[16], a2[16];
#pragma unroll
      for (int t = 0; t < 16; ++t) { ag[t] = 0.f; a2[t] = 0.f; }
      const float* Wa = wg + c0 + 16 * cgu;
      const float* Wb = wsp + 2 * (NN0 * HD) + c0 + 16 * cgu;
      const float* xc = xsT + row;
#pragma unroll 2
      for (int k = 0; k < NN0; ++k) {
        float xv = xc[k * SX1];
        const float* wa = Wa + k * HD;
        const float* wb = Wb + k * HD;
#pragma unroll
        for (int q = 0; q < 4; ++q) {
          float4 av = *(const float4*)(wa + 4 * q);
          float4 bv = *(const float4*)(wb + 4 * q);
          ag[4*q+0] += xv * av.x; ag[4*q+1] += xv * av.y;
          ag[4*q+2] += xv * av.z; ag[4*q+3] += xv * av.w;
          a2[4*q+0] += xv * bv.x; a2[4*q+1] += xv * bv.y;
          a2[4*q+2] += xv * bv.z; a2[4*q+3] += xv * bv.w;
        }
      }
      if (row < NN0) {
        float d1 = dis1[row], d0 = dis0[row];
#pragma unroll
        for (int t = 0; t < 16; ++t) {
          int cc = 16 * cgu + t;
          bufA[row * SP1 + cc] = d1 * ag[t];
          bufB[row * SP1 + cc] = d0 * a2[t];
          bufC[row * SP1 + cc] = a2[t];
        }
      }
    }
    __syncthreads();
    // ---- GCN: out = relu(dis1_i * (nsum(bufA) + bufA_i))
    for (int t = 0; t < 7; ++t) {
      int i = prg + 16 * t;
      if (i < NN0) {
        float2 self = *(const float2*)&bufA[i * SP1 + 2 * pcp];
        float2 acc = nsum2(i, bufA);
        acc.x += self.x; acc.y += self.y;
        float d1 = dis1[i];
        float2 o = make_float2(fmaxf(d1 * acc.x, 0.f), fmaxf(d1 * acc.y, 0.f));
        *(float2*)&h1b[i * FD + c0 + 2 * pcp] = o;
      }
    }
    __syncthreads();
    // ---- T' = dis0_i^2 * nsum(bufB)  -> bufA
    for (int t = 0; t < 7; ++t) {
      int i = prg + 16 * t;
      if (i < NN0) {
        float2 acc = nsum2(i, bufB);
        float s = dis0[i] * dis0[i];
        bufA[i * SP1 + 2 * pcp]     = s * acc.x;
        bufA[i * SP1 + 2 * pcp + 1] = s * acc.y;
      }
    }
    __syncthreads();
    // ---- cacc = 2*dis0_i*nsum(bufA) - P2raw  -> bufC
    for (int t = 0; t < 7; ++t) {
      int i = prg + 16 * t;
      if (i < NN0) {
        float2 acc = nsum2(i, bufA);
        float d0i = dis0[i];
        float2 old = *(const float2*)&bufC[i * SP1 + 2 * pcp];
        float2 nv = make_float2(2.f * d0i * acc.x - old.x,
                                2.f * d0i * acc.y - old.y);
        *(float2*)&bufC[i * SP1 + 2 * pcp] = nv;
      }
    }
    __syncthreads();
    // ---- sweep 2: P1 (wsp[1]) -> bufB(dis0-scaled); P0 (wsp[0]) -> bufA(raw)
    {
      float a1[16], a0[16];
#pragma unroll
      for (int t = 0; t < 16; ++t) { a1[t] = 0.f; a0[t] = 0.f; }
      const float* Wa = wsp + 1 * (NN0 * HD) + c0 + 16 * cgu;
      const float* Wb = wsp + 0              + c0 + 16 * cgu;
      const float* xc = xsT + row;
#pragma unroll 2
      for (int k = 0; k < NN0; ++k) {
        float xv = xc[k * SX1];
        const float* wa = Wa + k * HD;
        const float* wb = Wb + k * HD;
#pragma unroll
        for (int q = 0; q < 4; ++q) {
          float4 av = *(const float4*)(wa + 4 * q);
          float4 bv = *(const float4*)(wb + 4 * q);
          a1[4*q+0] += xv * av.x; a1[4*q+1] += xv * av.y;
          a1[4*q+2] += xv * av.z; a1[4*q+3] += xv * av.w;
          a0[4*q+0] += xv * bv.x; a0[4*q+1] += xv * bv.y;
          a0[4*q+2] += xv * bv.z; a0[4*q+3] += xv * bv.w;
        }
      }
      if (row < NN0) {
        float d0 = dis0[row];
#pragma unroll
        for (int t = 0; t < 16; ++t) {
          int cc = 16 * cgu + t;
          bufB[row * SP1 + cc] = d0 * a1[t];
          bufA[row * SP1 + cc] = a0[t];
        }
      }
    }
    __syncthreads();
    // ---- cheb out = relu(cacc - dis0_i*nsum(bufB) + bufA_i)
    for (int t = 0; t < 7; ++t) {
      int i = prg + 16 * t;
      if (i < NN0) {
        float2 acc = nsum2(i, bufB);
        float d0i = dis0[i];
        float2 cv = *(const float2*)&bufC[i * SP1 + 2 * pcp];
        float2 p0 = *(const float2*)&bufA[i * SP1 + 2 * pcp];
        float2 o = make_float2(fmaxf(cv.x - d0i * acc.x + p0.x, 0.f),
                               fmaxf(cv.y - d0i * acc.y + p0.y, 0.f));
        *(float2*)&h1b[i * FD + HD + c0 + 2 * pcp] = o;
      }
    }
    __syncthreads();
  }
}

// ---------------------------------------------------------------------------
// K2: pool1 — exact f32 scores (float2 reads), stable top-56, gather, adjp,
// readout x1 -> zbuf[7168..7679]
// ---------------------------------------------------------------------------
__global__ __launch_bounds__(512) void k_pool1(
    const float* __restrict__ h1, const float* __restrict__ adj,
    float* __restrict__ hp1, unsigned long long* __restrict__ adjp,
    float* __restrict__ zbuf, int b0)
{
  extern __shared__ float smemf[];
  float* hs = smemf;                               // 111*256
  unsigned* abits = (unsigned*)(hs + NN0 * FD);    // 444 (+pad)
  float* dinv = (float*)(abits + 448);             // 112
  float* sc = dinv + 112;                          // 112
  int* sel = (int*)(sc + 112);                     // 56

  const int tid = threadIdx.x, lane = tid & 63, wv = tid >> 6;
  const int bl = blockIdx.x;
  const int b = b0 + bl;
  const float* hb = h1 + (size_t)bl * (NN0 * FD);
  const float* ab = adj + (size_t)b * (NN0 * NN0);

  for (int q = tid; q < NN0 * 64; q += 512)
    ((float4*)hs)[q] = ((const float4*)hb)[q];
  for (int i = wv; i < NN0; i += 8) {
    unsigned long long m0 = __ballot(ab[i * NN0 + lane] != 0.0f);
    float a1v = (64 + lane < NN0) ? ab[i * NN0 + 64 + lane] : 0.0f;
    unsigned long long m1 = __ballot(a1v != 0.0f);
    if (lane == 0) {
      abits[i * 4 + 0] = (unsigned)m0; abits[i * 4 + 1] = (unsigned)(m0 >> 32);
      abits[i * 4 + 2] = (unsigned)m1; abits[i * 4 + 3] = (unsigned)(m1 >> 32);
      int d = __popcll(m0) + __popcll(m1);
      dinv[i] = (d > 0) ? (1.0f / (float)d) : 0.0f;
    }
  }
  __syncthreads();
  const int prg = tid >> 5, pcp = tid & 31;
  for (int t = 0; t < 7; ++t) {
    int i = prg + 16 * t;
    if (i < NN0) {
      float2 n0 = {0,0}, n1 = {0,0}, n2 = {0,0}, n3 = {0,0};
      const unsigned* rb = abits + i * 4;
#pragma unroll
      for (int w = 0; w < 4; ++w) {
        unsigned u = rb[w];
        while (u) {
          int j = (w << 5) + __builtin_ctz(u); u &= u - 1;
          const float* hr = hs + j * FD + 2 * pcp;
          float2 p0 = *(const float2*)(hr);
          float2 p1 = *(const float2*)(hr + 64);
          float2 p2 = *(const float2*)(hr + 128);
          float2 p3 = *(const float2*)(hr + 192);
          n0.x += p0.x; n0.y += p0.y; n1.x += p1.x; n1.y += p1.y;
          n2.x += p2.x; n2.y += p2.y; n3.x += p3.x; n3.y += p3.y;
        }
      }
      float di = dinv[i];
      const float* hi = hs + i * FD + 2 * pcp;
      float2 h0 = *(const float2*)(hi);
      float2 h1v = *(const float2*)(hi + 64);
      float2 h2v = *(const float2*)(hi + 128);
      float2 h3v = *(const float2*)(hi + 192);
      float s = fabsf(h0.x - di*n0.x) + fabsf(h0.y - di*n0.y)
              + fabsf(h1v.x - di*n1.x) + fabsf(h1v.y - di*n1.y)
              + fabsf(h2v.x - di*n2.x) + fabsf(h2v.y - di*n2.y)
              + fabsf(h3v.x - di*n3.x) + fabsf(h3v.y - di*n3.y);
#pragma unroll
      for (int off = 16; off; off >>= 1) s += __shfl_xor(s, off);
      if (pcp == 0) sc[i] = s;
    }
  }
  __syncthreads();
  if (tid < NN0) {
    float my = sc[tid];
    int cnt = 0;
    for (int j = 0; j < NN0; ++j) {
      float sj = sc[j];
      cnt += (sj > my) || (sj == my && j < tid);
    }
    if (cnt < NN1) sel[cnt] = tid;
  }
  __syncthreads();
  float* hpb = hp1 + (size_t)bl * (NN1 * FD);
  for (int r = wv; r < NN1; r += 8) {
    int i = sel[r];
    const float* hr = hs + i * FD + lane;
    float* dst = hpb + r * FD + lane;
    dst[0] = hr[0]; dst[64] = hr[64]; dst[128] = hr[128]; dst[192] = hr[192];
    int j2 = (lane < NN1) ? sel[lane] : 0;
    bool bit = (lane < NN1) && ((abits[i * 4 + (j2 >> 5)] >> (j2 & 31)) & 1);
    unsigned long long m = __ballot(bit);
    if (lane == 0) adjp[(size_t)bl * NN1 + r] = m;
  }
  __syncthreads();
  float* zb = zbuf + (size_t)bl * 8192;
  if (tid < FD) {
    float mx = -3.402823466e38f, sm2 = 0.0f;
    for (int r = 0; r < NN1; ++r) {
      float v = hs[sel[r] * FD + tid];
      mx = fmaxf(mx, v); sm2 += v;
    }
    zb[7168 + tid] = mx;
    zb[7168 + 256 + tid] = sm2 / 56.0f;
  }
}

// ---------------------------------------------------------------------------
// K3: stage-2 conv (56 nodes, K=256), same structure as stage1
// ---------------------------------------------------------------------------
__global__ __launch_bounds__(512) void k_stage2(
    const float* __restrict__ hp1, const unsigned long long* __restrict__ adjp,
    const float* __restrict__ wg, const float* __restrict__ wsp,
    float* __restrict__ h2)
{
  extern __shared__ float sm[];
  float* hT   = sm;                                // 256*65
  float* bufA = hT + 256 * SX2;                    // 56*66
  float* bufB = bufA + NN1 * SP2;
  float* bufC = bufB + NN1 * SP2;
  unsigned long long* rowm = (unsigned long long*)(bufC + NN1 * SP2); // 56
  float* dis0 = (float*)(rowm + 56);               // 64
  float* dis1 = dis0 + 64;                         // 64

  const int tid = threadIdx.x, lane = tid & 63, wv = tid >> 6;
  const int bl = blockIdx.x;
  const float* hb = hp1 + (size_t)bl * (NN1 * FD);

  for (int q = tid; q < 256 * SX2; q += 512) hT[q] = 0.0f;
  __syncthreads();
  for (int idx = tid; idx < NN1 * FD; idx += 512) {
    int i = idx >> 8, k = idx & 255;
    hT[k * SX2 + i] = hb[idx];
  }
  if (tid < NN1) {
    unsigned long long m = adjp[(size_t)bl * NN1 + tid];
    rowm[tid] = m;
    int d = __popcll(m);
    dis0[tid] = (d > 0) ? (1.0f / sqrtf((float)d)) : 0.0f;
    dis1[tid] = 1.0f / sqrtf((float)(d + 1));
  }
  __syncthreads();

  const int cgu = __builtin_amdgcn_readfirstlane(wv);  // 0..7, 8 cols each
  const int prg = tid >> 5, pcp = tid & 31;
  float* h2b = h2 + (size_t)bl * (NN1 * FD);

  auto nsum2 = [&](int i, const float* buf) {
    float2 acc = make_float2(0.f, 0.f);
    unsigned long long u = rowm[i];
    while (u) {
      int j = __builtin_ctzll(u); u &= u - 1;
      float2 p = *(const float2*)&buf[j * SP2 + 2 * pcp];
      acc.x += p.x; acc.y += p.y;
    }
    return acc;
  };

  for (int c = 0; c < 2; ++c) {
    const int c0 = c * 64;
    // sweep1: Pg -> bufA(d1), P2 -> bufB(d0), bufC(raw)
    {
      float ag[8], a2[8];
#pragma unroll
      for (int t = 0; t < 8; ++t) { ag[t] = 0.f; a2[t] = 0.f; }
      const float* Wa = wg + c0 + 8 * cgu;
      const float* Wb = wsp + 2 * (FD * HD) + c0 + 8 * cgu;
#pragma unroll 2
      for (int k = 0; k < FD; ++k) {
        float xv = hT[k * SX2 + lane];
        const float* wa = Wa + k * HD;
        const float* wb = Wb + k * HD;
#pragma unroll
        for (int q = 0; q < 2; ++q) {
          float4 av = *(const float4*)(wa + 4 * q);
          float4 bv = *(const float4*)(wb + 4 * q);
          ag[4*q+0] += xv * av.x; ag[4*q+1] += xv * av.y;
          ag[4*q+2] += xv * av.z; ag[4*q+3] += xv * av.w;
          a2[4*q+0] += xv * bv.x; a2[4*q+1] += xv * bv.y;
          a2[4*q+2] += xv * bv.z; a2[4*q+3] += xv * bv.w;
        }
      }
      if (lane < NN1) {
        float d1 = dis1[lane], d0 = dis0[lane];
#pragma unroll
        for (int t = 0; t < 8; ++t) {
          int cc = 8 * cgu + t;
          bufA[lane * SP2 + cc] = d1 * ag[t];
          bufB[lane * SP2 + cc] = d0 * a2[t];
          bufC[lane * SP2 + cc] = a2[t];
        }
      }
    }
    __syncthreads();
    // GCN
    for (int t = 0; t < 4; ++t) {
      int i = prg + 16 * t;
      if (i < NN1) {
        float2 self = *(const float2*)&bufA[i * SP2 + 2 * pcp];
        float2 acc = nsum2(i, bufA);
        acc.x += self.x; acc.y += self.y;
        float d1 = dis1[i];
        float2 o = make_float2(fmaxf(d1 * acc.x, 0.f), fmaxf(d1 * acc.y, 0.f));
        *(float2*)&h2b[i * FD + c0 + 2 * pcp] = o;
      }
    }
    __syncthreads();
    // T
    for (int t = 0; t < 4; ++t) {
      int i = prg + 16 * t;
      if (i < NN1) {
        float2 acc = nsum2(i, bufB);
        float s = dis0[i] * dis0[i];
        bufA[i * SP2 + 2 * pcp]     = s * acc.x;
        bufA[i * SP2 + 2 * pcp + 1] = s * acc.y;
      }
    }
    __syncthreads();
    // C
    for (int t = 0; t < 4; ++t) {
      int i = prg + 16 * t;
      if (i < NN1) {
        float2 acc = nsum2(i, bufA);
        float d0i = dis0[i];
        float2 old = *(const float2*)&bufC[i * SP2 + 2 * pcp];
        float2 nv = make_float2(2.f * d0i * acc.x - old.x,
                                2.f * d0i * acc.y - old.y);
        *(float2*)&bufC[i * SP2 + 2 * pcp] = nv;
      }
    }
    __syncthreads();
    // sweep2: P1 -> bufB(d0), P0 -> bufA(raw)
    {
      float a1[8], a0[8];
#pragma unroll
      for (int t = 0; t < 8; ++t) { a1[t] = 0.f; a0[t] = 0.f; }
      const float* Wa = wsp + 1 * (FD * HD) + c0 + 8 * cgu;
      const float* Wb = wsp + 0             + c0 + 8 * cgu;
#pragma unroll 2
      for (int k = 0; k < FD; ++k) {
        float xv = hT[k * SX2 + lane];
        const float* wa = Wa + k * HD;
        const float* wb = Wb + k * HD;
#pragma unroll
        for (int q = 0; q < 2; ++q) {
          float4 av = *(const float4*)(wa + 4 * q);
          float4 bv = *(const float4*)(wb + 4 * q);
          a1[4*q+0] += xv * av.x; a1[4*q+1] += xv * av.y;
          a1[4*q+2] += xv * av.z; a1[4*q+3] += xv * av.w;
          a0[4*q+0] += xv * bv.x; a0[4*q+1] += xv * bv.y;
          a0[4*q+2] += xv * bv.z; a0[4*q+3] += xv * bv.w;
        }
      }
      if (lane < NN1) {
        float d0 = dis0[lane];
#pragma unroll
        for (int t = 0; t < 8; ++t) {
          int cc = 8 * cgu + t;
          bufB[lane * SP2 + cc] = d0 * a1[t];
          bufA[lane * SP2 + cc] = a0[t];
        }
      }
    }
    __syncthreads();
    // F
    for (int t = 0; t < 4; ++t) {
      int i = prg + 16 * t;
      if (i < NN1) {
        float2 acc = nsum2(i, bufB);
        float d0i = dis0[i];
        float2 cv = *(const float2*)&bufC[i * SP2 + 2 * pcp];
        float2 p0 = *(const float2*)&bufA[i * SP2 + 2 * pcp];
        float2 o = make_float2(fmaxf(cv.x - d0i * acc.x + p0.x, 0.f),
                               fmaxf(cv.y - d0i * acc.y + p0.y, 0.f));
        *(float2*)&h2b[i * FD + HD + c0 + 2 * pcp] = o;
      }
    }
    __syncthreads();
  }
}

// ---------------------------------------------------------------------------
// K4: pool2 + readout; writes flat h into zbuf[0..7167], x2 -> zbuf[7680..]
// ---------------------------------------------------------------------------
__global__ __launch_bounds__(256) void k_pool2(
    const float* __restrict__ h2, const unsigned long long* __restrict__ adjp,
    float* __restrict__ zbuf)
{
  extern __shared__ float smemf[];
  float* hs = smemf;                                        // 56*256
  unsigned long long* rowm = (unsigned long long*)(hs + NN1 * FD);
  float* dinv = (float*)(rowm + 56);
  float* sc = dinv + 64;
  int* sel = (int*)(sc + 64);

  const int tid = threadIdx.x, lane = tid & 63, wv = tid >> 6;
  const int bl = blockIdx.x;
  const float* hb = h2 + (size_t)bl * (NN1 * FD);
  for (int q = tid; q < NN1 * 64; q += 256)
    ((float4*)hs)[q] = ((const float4*)hb)[q];
  if (tid < NN1) {
    unsigned long long m = adjp[(size_t)bl * NN1 + tid];
    rowm[tid] = m;
    int d = __popcll(m);
    dinv[tid] = (d > 0) ? (1.0f / (float)d) : 0.0f;
  }
  __syncthreads();
  const int prg = tid >> 5, pcp = tid & 31;  // prg 0..7
  for (int t = 0; t < 7; ++t) {
    int i = prg + 8 * t;  // 0..55
    float2 n0 = {0,0}, n1 = {0,0}, n2 = {0,0}, n3 = {0,0};
    unsigned long long u = rowm[i];
    while (u) {
      int j = __builtin_ctzll(u); u &= u - 1;
      const float* hr = hs + j * FD + 2 * pcp;
      float2 p0 = *(const float2*)(hr);
      float2 p1 = *(const float2*)(hr + 64);
      float2 p2 = *(const float2*)(hr + 128);
      float2 p3 = *(const float2*)(hr + 192);
      n0.x += p0.x; n0.y += p0.y; n1.x += p1.x; n1.y += p1.y;
      n2.x += p2.x; n2.y += p2.y; n3.x += p3.x; n3.y += p3.y;
    }
    float di = dinv[i];
    const float* hi = hs + i * FD + 2 * pcp;
    float2 h0 = *(const float2*)(hi);
    float2 h1v = *(const float2*)(hi + 64);
    float2 h2v = *(const float2*)(hi + 128);
    float2 h3v = *(const float2*)(hi + 192);
    float s = fabsf(h0.x - di*n0.x) + fabsf(h0.y - di*n0.y)
            + fabsf(h1v.x - di*n1.x) + fabsf(h1v.y - di*n1.y)
            + fabsf(h2v.x - di*n2.x) + fabsf(h2v.y - di*n2.y)
            + fabsf(h3v.x - di*n3.x) + fabsf(h3v.y - di*n3.y);
#pragma unroll
    for (int off = 16; off; off >>= 1) s += __shfl_xor(s, off);
    if (pcp == 0) sc[i] = s;
  }
  __syncthreads();
  if (tid < NN1) {
    float my = sc[tid];
    int cnt = 0;
    for (int j = 0; j < NN1; ++j) {
      float sj = sc[j];
      cnt += (sj > my) || (sj == my && j < tid);
    }
    if (cnt < NN2) sel[cnt] = tid;
  }
  __syncthreads();
  float* zb = zbuf + (size_t)bl * 8192;
  for (int r = wv; r < NN2; r += 4) {
    const float* hr = hs + sel[r] * FD + lane;
    float* dst = zb + r * FD + lane;
    dst[0] = hr[0]; dst[64] = hr[64]; dst[128] = hr[128]; dst[192] = hr[192];
  }
  {
    float mx = -3.402823466e38f, sm2 = 0.0f;
    for (int r = 0; r < NN2; ++r) {
      float v = hs[sel[r] * FD + tid];
      mx = fmaxf(mx, v); sm2 += v;
    }
    zb[7680 + tid] = mx;
    zb[7936 + tid] = sm2 / 28.0f;
  }
}

// ---------------------------------------------------------------------------
// K5: f = relu(z @ lin1_w + b1), z read contiguously from zbuf
// ---------------------------------------------------------------------------
__global__ __launch_bounds__(256) void k_lin1(
    const float* __restrict__ zbuf, const float* __restrict__ w,
    const float* __restrict__ bias, float* __restrict__ fbuf)
{
  __shared__ float zt[32][36];
  __shared__ float wt[32][64];
  const int tid = threadIdx.x, col = tid & 63, rg = tid >> 6;
  const int g0 = blockIdx.x * 32;
  const int n0 = blockIdx.y * 64;
  float acc[8];
#pragma unroll
  for (int t = 0; t < 8; ++t) acc[t] = 0.0f;
  for (int kb = 0; kb < 256; ++kb) {
    int k0 = kb * 32;
#pragma unroll
    for (int q = 0; q < 4; ++q) {
      int e = tid + 256 * q;
      int k = e & 31, m = e >> 5;
      zt[m][k] = zbuf[(size_t)(g0 + m) * 8192 + k0 + k];
    }
#pragma unroll
    for (int q = 0; q < 8; ++q) {
      int e = tid + 256 * q;
      int cc = e & 63, kr = e >> 6;
      wt[kr][cc] = w[(size_t)(k0 + kr) * 256 + n0 + cc];
    }
    __syncthreads();
#pragma unroll
    for (int k = 0; k < 32; k += 4) {
      float w0 = wt[k][col], w1 = wt[k+1][col], w2 = wt[k+2][col], w3 = wt[k+3][col];
#pragma unroll
      for (int t = 0; t < 8; ++t) {
        int m = rg * 8 + t;
        float4 zq = *(const float4*)(&zt[m][k]);
        acc[t] += zq.x * w0 + zq.y * w1 + zq.z * w2 + zq.w * w3;
      }
    }
    __syncthreads();
  }
#pragma unroll
  for (int t = 0; t < 8; ++t) {
    int m = rg * 8 + t;
    float v = acc[t] + bias[n0 + col];
    fbuf[(size_t)(g0 + m) * 256 + n0 + col] = fmaxf(v, 0.0f);
  }
}

// ---------------------------------------------------------------------------
// K6: features = relu(f @ lin2_w + b2); x_lo = softmax(features)
// ---------------------------------------------------------------------------
__global__ __launch_bounds__(128) void k_head(
    const float* __restrict__ fbuf, const float* __restrict__ w2,
    const float* __restrict__ b2, float* __restrict__ out, int b0)
{
  __shared__ __align__(16) float fs[256];
  __shared__ float red[2];
  const int tid = threadIdx.x, lane = tid & 63, wv = tid >> 6;
  const int bl = blockIdx.x, b = b0 + bl;
  for (int i = tid; i < 256; i += 128) fs[i] = fbuf[(size_t)bl * 256 + i];
  __syncthreads();
  float acc = b2[tid];
  for (int k = 0; k < 256; k += 4) {
    float4 fq = *(const float4*)(fs + k);
    acc += fq.x * w2[(k + 0) * 128 + tid] + fq.y * w2[(k + 1) * 128 + tid]
         + fq.z * w2[(k + 2) * 128 + tid] + fq.w * w2[(k + 3) * 128 + tid];
  }
  float feat = fmaxf(acc, 0.0f);
  out[(size_t)(NB * 128) + (size_t)b * 128 + tid] = feat;
  float m = feat;
  for (int off = 32; off; off >>= 1) m = fmaxf(m, __shfl_xor(m, off));
  if (lane == 0) red[wv] = m;
  __syncthreads();
  m = fmaxf(red[0], red[1]);
  float e = expf(feat - m);
  float s = e;
  for (int off = 32; off; off >>= 1) s += __shfl_xor(s, off);
  __syncthreads();
  if (lane == 0) red[wv] = s;
  __syncthreads();
  s = red[0] + red[1];
  out[(size_t)b * 128 + tid] = e / s;
}

// ---------------------------------------------------------------------------
extern "C" void kernel_launch(void* const* d_in, const int* in_sizes, int n_in,
                              void* d_out, int out_size, void* d_ws, size_t ws_size,
                              hipStream_t stream) {
  const float* x    = (const float*)d_in[0];
  const float* adj  = (const float*)d_in[1];
  const float* wg1  = (const float*)d_in[2];
  const float* wsp1 = (const float*)d_in[3];
  const float* wg2  = (const float*)d_in[4];
  const float* wsp2 = (const float*)d_in[5];
  const float* l1w  = (const float*)d_in[6];
  const float* l1b  = (const float*)d_in[7];
  const float* l2w  = (const float*)d_in[8];
  const float* l2b  = (const float*)d_in[9];
  float* out = (float*)d_out;

  auto al = [](size_t v) { return (v + 255) & ~(size_t)255; };
  size_t oh1, ohp1, oadjp, oz, of;
  auto plan = [&](int g) -> size_t {
    size_t o = 0;
    oh1 = o;   o += al((size_t)g * NN0 * FD * 4);   // h1 (h2 overlay)
    ohp1 = o;  o += al((size_t)g * NN1 * FD * 4);
    oadjp = o; o += al((size_t)g * NN1 * 8);
    oz = o;    o += al((size_t)g * 8192 * 4);
    of = o;    o += al((size_t)g * FD * 4);
    return o;
  };
  int G = 2048;
  while (G > 64 && plan(G) > ws_size) G >>= 1;
  if (plan(G) > ws_size) return;

  char* wsb = (char*)d_ws;
  float* h1  = (float*)(wsb + oh1);
  float* hp1 = (float*)(wsb + ohp1);
  unsigned long long* adjp = (unsigned long long*)(wsb + oadjp);
  float* zbuf = (float*)(wsb + oz);
  float* fbuf = (float*)(wsb + of);

  const size_t LDS1 = (size_t)(NN0 * SX1 + 3 * NN0 * SP1 + 448 + 224) * 4; // ~147.9KB
  const size_t LDS2 = (size_t)(NN0 * FD + 448 + 112 + 112 + 56) * 4;       // ~116.6KB
  const size_t LDS3 = (size_t)(256 * SX2 + 3 * NN1 * SP2 + 112 + 128) * 4; // ~111.9KB
  const size_t LDS4 = (size_t)(NN1 * FD + 112 + 64 + 64 + 32) * 4;         // ~58.4KB

  for (int b0 = 0; b0 < NB; b0 += G) {
    k_stage1<<<G, 512, LDS1, stream>>>(x, adj, wg1, wsp1, h1, b0);
    k_pool1<<<G, 512, LDS2, stream>>>(h1, adj, hp1, adjp, zbuf, b0);
    k_stage2<<<G, 512, LDS3, stream>>>(hp1, adjp, wg2, wsp2, h1);
    k_pool2<<<G, 256, LDS4, stream>>>(h1, adjp, zbuf);
    k_lin1<<<dim3(G / 32, 4), 256, 0, stream>>>(zbuf, l1w, l1b, fbuf);
    k_head<<<G, 128, 0, stream>>>(fbuf, l2w, l2b, out, b0);
  }
}

// Round 3
// 6319.769 us; speedup vs baseline: 1.3883x; 1.3883x over previous
//
#include <hip/hip_runtime.h>
#include <hip/hip_bf16.h>

#define NB   2048
#define NN0  111
#define NN1  56
#define NN2  28
#define FD   256
#define HD   128

// ---------------------------------------------------------------------------
// K1: stage-1 conv. One block/graph, 512 thr = (col 0..63) x (wave 0..7).
// GEMM: xs broadcast b128 reads, 4 weight matrices at once (16 FMA / b128).
// Props: wave-uniform row, lane = col, pre-scaled buffers (pure adds).
// LDS: xs[111][112] + bufA[111][64] + bufB[111][64] + abits + dis = 109,248 B
// ---------------------------------------------------------------------------
__global__ __launch_bounds__(512) void k_stage1(
    const float* __restrict__ x, const float* __restrict__ adj,
    const float* __restrict__ wg, const float* __restrict__ wsp,
    float* __restrict__ h1, int b0)
{
  extern __shared__ float sm[];
  float* xs   = sm;                                // 111*112 = 12432
  float* bufA = xs + NN0 * 112;                    // 111*64 = 7104
  float* bufB = bufA + NN0 * 64;                   // 7104
  unsigned* abits = (unsigned*)(bufB + NN0 * 64);  // 448 u32
  float* dis0 = (float*)(abits + 448);             // 112
  float* dis1 = dis0 + 112;                        // 112

  const int tid  = threadIdx.x;
  const int lane = tid & 63;   // col
  const int wv   = tid >> 6;   // row group
  const int b    = b0 + blockIdx.x;
  const float* xb = x   + (size_t)b * (NN0 * NN0);
  const float* ab = adj + (size_t)b * (NN0 * NN0);

  for (int idx = tid; idx < NN0 * NN0; idx += 512) {
    int i = idx / NN0, k = idx - i * NN0;
    xs[i * 112 + k] = xb[idx];
  }
  for (int i = wv; i < NN0; i += 8) {
    unsigned long long m0 = __ballot(ab[i * NN0 + lane] != 0.0f);
    float a1v = (64 + lane < NN0) ? ab[i * NN0 + 64 + lane] : 0.0f;
    unsigned long long m1 = __ballot(a1v != 0.0f);
    if (lane == 0) {
      abits[i * 4 + 0] = (unsigned)m0; abits[i * 4 + 1] = (unsigned)(m0 >> 32);
      abits[i * 4 + 2] = (unsigned)m1; abits[i * 4 + 3] = (unsigned)(m1 >> 32);
      int d = __popcll(m0) + __popcll(m1);
      dis0[i] = (d > 0) ? (1.0f / sqrtf((float)d)) : 0.0f;
      dis1[i] = 1.0f / sqrtf((float)(d + 1));
    }
  }
  __syncthreads();

  // neighbor sum over LDS buffer (wave-uniform row i, lane = col)
  auto nsum = [&](int i, const float* buf) {
    float acc = 0.0f;
    const unsigned* rb = abits + i * 4;
#pragma unroll
    for (int w4 = 0; w4 < 4; ++w4) {
      unsigned u = rb[w4];
      while (u) {
        int j = (w4 << 5) + __builtin_ctz(u); u &= u - 1;
        acc += buf[j * 64 + lane];
      }
    }
    return acc;
  };

  float* h1b = h1 + (size_t)blockIdx.x * (NN0 * FD);

  for (int c = 0; c < 2; ++c) {
    const int c0 = c * 64;
    // ---- one sweep over xs: all 4 weight matrices ----
    float aG[14], a2[14], a1[14], a0v[14];
#pragma unroll
    for (int t = 0; t < 14; ++t) { aG[t] = 0.f; a2[t] = 0.f; a1[t] = 0.f; a0v[t] = 0.f; }
    const float* pG = wg  + c0 + lane;
    const float* p2 = wsp + 2 * (NN0 * HD) + c0 + lane;
    const float* p1 = wsp + 1 * (NN0 * HD) + c0 + lane;
    const float* p0 = wsp + c0 + lane;
    for (int kq = 0; kq < 27; ++kq) {
      int k0 = kq * 4;
      float g0 = pG[(k0+0)*HD], g1 = pG[(k0+1)*HD], g2 = pG[(k0+2)*HD], g3 = pG[(k0+3)*HD];
      float s0 = p2[(k0+0)*HD], s1 = p2[(k0+1)*HD], s2 = p2[(k0+2)*HD], s3 = p2[(k0+3)*HD];
      float u0 = p1[(k0+0)*HD], u1 = p1[(k0+1)*HD], u2 = p1[(k0+2)*HD], u3 = p1[(k0+3)*HD];
      float v0 = p0[(k0+0)*HD], v1 = p0[(k0+1)*HD], v2 = p0[(k0+2)*HD], v3 = p0[(k0+3)*HD];
#pragma unroll
      for (int t = 0; t < 14; ++t) {
        int r = wv + 8 * t;
        if (r < NN0) {
          float4 xq = *(const float4*)(xs + r * 112 + k0);
          aG[t]  += xq.x*g0 + xq.y*g1 + xq.z*g2 + xq.w*g3;
          a2[t]  += xq.x*s0 + xq.y*s1 + xq.z*s2 + xq.w*s3;
          a1[t]  += xq.x*u0 + xq.y*u1 + xq.z*u2 + xq.w*u3;
          a0v[t] += xq.x*v0 + xq.y*v1 + xq.z*v2 + xq.w*v3;
        }
      }
    }
#pragma unroll
    for (int k = 108; k < 111; ++k) {
      float gv = pG[k*HD], sv = p2[k*HD], uv = p1[k*HD], vv = p0[k*HD];
#pragma unroll
      for (int t = 0; t < 14; ++t) {
        int r = wv + 8 * t;
        if (r < NN0) {
          float xv = xs[r * 112 + k];
          aG[t] += xv * gv; a2[t] += xv * sv; a1[t] += xv * uv; a0v[t] += xv * vv;
        }
      }
    }

    // ---- GCN: bufA = d1*PG ----
#pragma unroll
    for (int t = 0; t < 14; ++t) {
      int r = wv + 8 * t;
      if (r < NN0) bufA[r * 64 + lane] = dis1[r] * aG[t];
    }
    __syncthreads();
    for (int t = 0; t < 14; ++t) {
      int i = wv + 8 * t;
      if (i < NN0) {
        float acc = bufA[i * 64 + lane] + nsum(i, bufA);
        h1b[i * FD + c0 + lane] = fmaxf(dis1[i] * acc, 0.0f);
      }
    }
    __syncthreads();
    // ---- Cheb. bufA = d0*P2 ----
#pragma unroll
    for (int t = 0; t < 14; ++t) {
      int r = wv + 8 * t;
      if (r < NN0) bufA[r * 64 + lane] = dis0[r] * a2[t];
    }
    __syncthreads();
    // U phase: bufB_i = -d0_i^2 * sum_j bufA_j ; cacc = -P2_raw
    float cacc[14];
    for (int t = 0; t < 14; ++t) {
      int i = wv + 8 * t;
      if (i < NN0) {
        float s = nsum(i, bufA);
        bufB[i * 64 + lane] = -dis0[i] * dis0[i] * s;
        cacc[t] = -a2[t];
      } else cacc[t] = 0.f;
    }
    __syncthreads();
    // V phase (reads bufB) + write bufA = d0*P1 (bufA free since U done)
#pragma unroll
    for (int t = 0; t < 14; ++t) {
      int r = wv + 8 * t;
      if (r < NN0) bufA[r * 64 + lane] = dis0[r] * a1[t];
    }
    for (int t = 0; t < 14; ++t) {
      int i = wv + 8 * t;
      if (i < NN0) {
        float v = nsum(i, bufB);
        cacc[t] -= 2.0f * dis0[i] * v;
      }
    }
    __syncthreads();
    // T1 + output: out = cacc - d0_i*sum(bufA) + P0_raw
    for (int t = 0; t < 14; ++t) {
      int i = wv + 8 * t;
      if (i < NN0) {
        float tl = nsum(i, bufA);
        float o = cacc[t] - dis0[i] * tl + a0v[t];
        h1b[i * FD + HD + c0 + lane] = fmaxf(o, 0.0f);
      }
    }
    __syncthreads();
  }
}

// ---------------------------------------------------------------------------
// K2: pool1 (round-1 proven pattern) — exact f32 scores, stable top-56,
// gather hp1 + adjp bits, readout x1 -> zbuf[7168..7679]
// ---------------------------------------------------------------------------
__global__ __launch_bounds__(512) void k_pool1(
    const float* __restrict__ h1, const float* __restrict__ adj,
    float* __restrict__ hp1, unsigned long long* __restrict__ adjp,
    float* __restrict__ zbuf, int b0)
{
  extern __shared__ float smemf[];
  float* hs = smemf;                               // 111*256
  unsigned* abits = (unsigned*)(hs + NN0 * FD);    // 448
  float* dinv = (float*)(abits + 448);             // 112
  float* sc = dinv + 112;                          // 112
  int* sel = (int*)(sc + 112);                     // 56

  const int tid = threadIdx.x, lane = tid & 63, wv = tid >> 6;
  const int bl = blockIdx.x;
  const int b = b0 + bl;
  const float* hb = h1 + (size_t)bl * (NN0 * FD);
  const float* ab = adj + (size_t)b * (NN0 * NN0);

  for (int q = tid; q < NN0 * 64; q += 512)
    ((float4*)hs)[q] = ((const float4*)hb)[q];
  for (int i = wv; i < NN0; i += 8) {
    unsigned long long m0 = __ballot(ab[i * NN0 + lane] != 0.0f);
    float a1v = (64 + lane < NN0) ? ab[i * NN0 + 64 + lane] : 0.0f;
    unsigned long long m1 = __ballot(a1v != 0.0f);
    if (lane == 0) {
      abits[i * 4 + 0] = (unsigned)m0; abits[i * 4 + 1] = (unsigned)(m0 >> 32);
      abits[i * 4 + 2] = (unsigned)m1; abits[i * 4 + 3] = (unsigned)(m1 >> 32);
      int d = __popcll(m0) + __popcll(m1);
      dinv[i] = (d > 0) ? (1.0f / (float)d) : 0.0f;
    }
  }
  __syncthreads();
  for (int i = wv; i < NN0; i += 8) {
    float nb0 = 0, nb1 = 0, nb2 = 0, nb3 = 0;
    const unsigned* rb = abits + i * 4;
#pragma unroll
    for (int w4 = 0; w4 < 4; ++w4) {
      unsigned u = rb[w4];
      while (u) {
        int j = (w4 << 5) + __builtin_ctz(u); u &= u - 1;
        const float* hr = hs + j * FD + lane;
        nb0 += hr[0]; nb1 += hr[64]; nb2 += hr[128]; nb3 += hr[192];
      }
    }
    const float* hi = hs + i * FD + lane;
    float di = dinv[i];
    float s = fabsf(hi[0] - di * nb0) + fabsf(hi[64] - di * nb1)
            + fabsf(hi[128] - di * nb2) + fabsf(hi[192] - di * nb3);
    for (int off = 32; off; off >>= 1) s += __shfl_xor(s, off);
    if (lane == 0) sc[i] = s;
  }
  __syncthreads();
  if (tid < NN0) {
    float my = sc[tid];
    int cnt = 0;
    for (int j = 0; j < NN0; ++j) {
      float sj = sc[j];
      cnt += (sj > my) || (sj == my && j < tid);
    }
    if (cnt < NN1) sel[cnt] = tid;
  }
  __syncthreads();
  float* hpb = hp1 + (size_t)bl * (NN1 * FD);
  for (int r = wv; r < NN1; r += 8) {
    int i = sel[r];
    const float* hr = hs + i * FD + lane;
    float* dst = hpb + r * FD + lane;
    dst[0] = hr[0]; dst[64] = hr[64]; dst[128] = hr[128]; dst[192] = hr[192];
    int j2 = (lane < NN1) ? sel[lane] : 0;
    bool bit = (lane < NN1) && ((abits[i * 4 + (j2 >> 5)] >> (j2 & 31)) & 1);
    unsigned long long m = __ballot(bit);
    if (lane == 0) adjp[(size_t)bl * NN1 + r] = m;
  }
  __syncthreads();
  float* zb = zbuf + (size_t)bl * 8192;
  if (tid < FD) {
    float mx = -3.402823466e38f, sm2 = 0.0f;
    for (int r = 0; r < NN1; ++r) {
      float v = hs[sel[r] * FD + tid];
      mx = fmaxf(mx, v); sm2 += v;
    }
    zb[7168 + tid] = mx;
    zb[7424 + tid] = sm2 / 56.0f;
  }
}

// ---------------------------------------------------------------------------
// K3: stage-2 conv (56 nodes, K=256), same 4-matrix-sweep structure.
// LDS: hs[56][256] + bufA/bufB[56][64] + rowm + dis = 86,976 B
// ---------------------------------------------------------------------------
__global__ __launch_bounds__(512) void k_stage2(
    const float* __restrict__ hp1, const unsigned long long* __restrict__ adjp,
    const float* __restrict__ wg, const float* __restrict__ wsp,
    float* __restrict__ h2)
{
  extern __shared__ float sm[];
  float* hs   = sm;                                // 56*256 = 14336
  float* bufA = hs + NN1 * FD;                     // 3584
  float* bufB = bufA + NN1 * 64;                   // 3584
  unsigned long long* rowm = (unsigned long long*)(bufB + NN1 * 64); // 56
  float* dis0 = (float*)(rowm + 56);               // 64
  float* dis1 = dis0 + 64;                         // 64

  const int tid = threadIdx.x, lane = tid & 63, wv = tid >> 6;
  const int bl = blockIdx.x;
  const float* hb = hp1 + (size_t)bl * (NN1 * FD);
  for (int q = tid; q < NN1 * 64; q += 512)
    ((float4*)hs)[q] = ((const float4*)hb)[q];
  if (tid < NN1) {
    unsigned long long m = adjp[(size_t)bl * NN1 + tid];
    rowm[tid] = m;
    int d = __popcll(m);
    dis0[tid] = (d > 0) ? (1.0f / sqrtf((float)d)) : 0.0f;
    dis1[tid] = 1.0f / sqrtf((float)(d + 1));
  }
  __syncthreads();

  auto nsum = [&](int i, const float* buf) {
    float acc = 0.0f;
    unsigned long long u = rowm[i];
    while (u) {
      int j = __builtin_ctzll(u); u &= u - 1;
      acc += buf[j * 64 + lane];
    }
    return acc;
  };

  float* h2b = h2 + (size_t)bl * (NN1 * FD);

  for (int c = 0; c < 2; ++c) {
    const int c0 = c * 64;
    float aG[7], a2[7], a1[7], a0v[7];
#pragma unroll
    for (int t = 0; t < 7; ++t) { aG[t] = 0.f; a2[t] = 0.f; a1[t] = 0.f; a0v[t] = 0.f; }
    const float* pG = wg  + c0 + lane;
    const float* p2 = wsp + 2 * (FD * HD) + c0 + lane;
    const float* p1 = wsp + 1 * (FD * HD) + c0 + lane;
    const float* p0 = wsp + c0 + lane;
    for (int kq = 0; kq < 64; ++kq) {
      int k0 = kq * 4;
      float g0 = pG[(k0+0)*HD], g1 = pG[(k0+1)*HD], g2 = pG[(k0+2)*HD], g3 = pG[(k0+3)*HD];
      float s0 = p2[(k0+0)*HD], s1 = p2[(k0+1)*HD], s2 = p2[(k0+2)*HD], s3 = p2[(k0+3)*HD];
      float u0 = p1[(k0+0)*HD], u1 = p1[(k0+1)*HD], u2 = p1[(k0+2)*HD], u3 = p1[(k0+3)*HD];
      float v0 = p0[(k0+0)*HD], v1 = p0[(k0+1)*HD], v2 = p0[(k0+2)*HD], v3 = p0[(k0+3)*HD];
#pragma unroll
      for (int t = 0; t < 7; ++t) {
        int r = wv + 8 * t;
        float4 xq = *(const float4*)(hs + r * FD + k0);
        aG[t]  += xq.x*g0 + xq.y*g1 + xq.z*g2 + xq.w*g3;
        a2[t]  += xq.x*s0 + xq.y*s1 + xq.z*s2 + xq.w*s3;
        a1[t]  += xq.x*u0 + xq.y*u1 + xq.z*u2 + xq.w*u3;
        a0v[t] += xq.x*v0 + xq.y*v1 + xq.z*v2 + xq.w*v3;
      }
    }
    // GCN
#pragma unroll
    for (int t = 0; t < 7; ++t) bufA[(wv + 8*t) * 64 + lane] = dis1[wv + 8*t] * aG[t];
    __syncthreads();
#pragma unroll
    for (int t = 0; t < 7; ++t) {
      int i = wv + 8 * t;
      float acc = bufA[i * 64 + lane] + nsum(i, bufA);
      h2b[i * FD + c0 + lane] = fmaxf(dis1[i] * acc, 0.0f);
    }
    __syncthreads();
#pragma unroll
    for (int t = 0; t < 7; ++t) bufA[(wv + 8*t) * 64 + lane] = dis0[wv + 8*t] * a2[t];
    __syncthreads();
    float cacc[7];
#pragma unroll
    for (int t = 0; t < 7; ++t) {
      int i = wv + 8 * t;
      float s = nsum(i, bufA);
      bufB[i * 64 + lane] = -dis0[i] * dis0[i] * s;
      cacc[t] = -a2[t];
    }
    __syncthreads();
#pragma unroll
    for (int t = 0; t < 7; ++t) bufA[(wv + 8*t) * 64 + lane] = dis0[wv + 8*t] * a1[t];
#pragma unroll
    for (int t = 0; t < 7; ++t) {
      int i = wv + 8 * t;
      float v = nsum(i, bufB);
      cacc[t] -= 2.0f * dis0[i] * v;
    }
    __syncthreads();
#pragma unroll
    for (int t = 0; t < 7; ++t) {
      int i = wv + 8 * t;
      float tl = nsum(i, bufA);
      float o = cacc[t] - dis0[i] * tl + a0v[t];
      h2b[i * FD + HD + c0 + lane] = fmaxf(o, 0.0f);
    }
    __syncthreads();
  }
}

// ---------------------------------------------------------------------------
// K4: pool2 + readout (round-1 pattern); flat h -> zbuf[0..7167], x2 -> 7680+
// ---------------------------------------------------------------------------
__global__ __launch_bounds__(256) void k_pool2(
    const float* __restrict__ h2, const unsigned long long* __restrict__ adjp,
    float* __restrict__ zbuf)
{
  extern __shared__ float smemf[];
  float* hs = smemf;                                        // 56*256
  unsigned long long* rowm = (unsigned long long*)(hs + NN1 * FD);
  float* dinv = (float*)(rowm + 56);
  float* sc = dinv + 64;
  int* sel = (int*)(sc + 64);

  const int tid = threadIdx.x, lane = tid & 63, wv = tid >> 6;
  const int bl = blockIdx.x;
  const float* hb = h2 + (size_t)bl * (NN1 * FD);
  for (int q = tid; q < NN1 * 64; q += 256)
    ((float4*)hs)[q] = ((const float4*)hb)[q];
  if (tid < NN1) {
    unsigned long long m = adjp[(size_t)bl * NN1 + tid];
    rowm[tid] = m;
    int d = __popcll(m);
    dinv[tid] = (d > 0) ? (1.0f / (float)d) : 0.0f;
  }
  __syncthreads();
  for (int i = wv; i < NN1; i += 4) {
    float nb0 = 0, nb1 = 0, nb2 = 0, nb3 = 0;
    unsigned long long u = rowm[i];
    while (u) {
      int j = __builtin_ctzll(u); u &= u - 1;
      const float* hr = hs + j * FD + lane;
      nb0 += hr[0]; nb1 += hr[64]; nb2 += hr[128]; nb3 += hr[192];
    }
    const float* hi = hs + i * FD + lane;
    float di = dinv[i];
    float s = fabsf(hi[0] - di * nb0) + fabsf(hi[64] - di * nb1)
            + fabsf(hi[128] - di * nb2) + fabsf(hi[192] - di * nb3);
    for (int off = 32; off; off >>= 1) s += __shfl_xor(s, off);
    if (lane == 0) sc[i] = s;
  }
  __syncthreads();
  if (tid < NN1) {
    float my = sc[tid];
    int cnt = 0;
    for (int j = 0; j < NN1; ++j) {
      float sj = sc[j];
      cnt += (sj > my) || (sj == my && j < tid);
    }
    if (cnt < NN2) sel[cnt] = tid;
  }
  __syncthreads();
  float* zb = zbuf + (size_t)bl * 8192;
  for (int r = wv; r < NN2; r += 4) {
    const float* hr = hs + sel[r] * FD + lane;
    float* dst = zb + r * FD + lane;
    dst[0] = hr[0]; dst[64] = hr[64]; dst[128] = hr[128]; dst[192] = hr[192];
  }
  {
    float mx = -3.402823466e38f, sm2 = 0.0f;
    for (int r = 0; r < NN2; ++r) {
      float v = hs[sel[r] * FD + tid];
      mx = fmaxf(mx, v); sm2 += v;
    }
    zb[7680 + tid] = mx;
    zb[7936 + tid] = sm2 / 28.0f;
  }
}

// ---------------------------------------------------------------------------
// K5: f = relu(z @ lin1_w + b1), z contiguous in zbuf
// ---------------------------------------------------------------------------
__global__ __launch_bounds__(256) void k_lin1(
    const float* __restrict__ zbuf, const float* __restrict__ w,
    const float* __restrict__ bias, float* __restrict__ fbuf)
{
  __shared__ float zt[32][36];
  __shared__ float wt[32][64];
  const int tid = threadIdx.x, col = tid & 63, rg = tid >> 6;
  const int g0 = blockIdx.x * 32;
  const int n0 = blockIdx.y * 64;
  float acc[8];
#pragma unroll
  for (int t = 0; t < 8; ++t) acc[t] = 0.0f;
  for (int kb = 0; kb < 256; ++kb) {
    int k0 = kb * 32;
#pragma unroll
    for (int q = 0; q < 4; ++q) {
      int e = tid + 256 * q;
      int k = e & 31, m = e >> 5;
      zt[m][k] = zbuf[(size_t)(g0 + m) * 8192 + k0 + k];
    }
#pragma unroll
    for (int q = 0; q < 8; ++q) {
      int e = tid + 256 * q;
      int cc = e & 63, kr = e >> 6;
      wt[kr][cc] = w[(size_t)(k0 + kr) * 256 + n0 + cc];
    }
    __syncthreads();
#pragma unroll
    for (int k = 0; k < 32; k += 4) {
      float w0 = wt[k][col], w1 = wt[k+1][col], w2 = wt[k+2][col], w3 = wt[k+3][col];
#pragma unroll
      for (int t = 0; t < 8; ++t) {
        int m = rg * 8 + t;
        float4 zq = *(const float4*)(&zt[m][k]);
        acc[t] += zq.x * w0 + zq.y * w1 + zq.z * w2 + zq.w * w3;
      }
    }
    __syncthreads();
  }
#pragma unroll
  for (int t = 0; t < 8; ++t) {
    int m = rg * 8 + t;
    float v = acc[t] + bias[n0 + col];
    fbuf[(size_t)(g0 + m) * 256 + n0 + col] = fmaxf(v, 0.0f);
  }
}

// ---------------------------------------------------------------------------
// K6: features = relu(f @ lin2_w + b2); x_lo = softmax(features)
// ---------------------------------------------------------------------------
__global__ __launch_bounds__(128) void k_head(
    const float* __restrict__ fbuf, const float* __restrict__ w2,
    const float* __restrict__ b2, float* __restrict__ out, int b0)
{
  __shared__ __align__(16) float fs[256];
  __shared__ float red[2];
  const int tid = threadIdx.x, lane = tid & 63, wv = tid >> 6;
  const int bl = blockIdx.x, b = b0 + bl;
  for (int i = tid; i < 256; i += 128) fs[i] = fbuf[(size_t)bl * 256 + i];
  __syncthreads();
  float acc = b2[tid];
  for (int k = 0; k < 256; k += 4) {
    float4 fq = *(const float4*)(fs + k);
    acc += fq.x * w2[(k + 0) * 128 + tid] + fq.y * w2[(k + 1) * 128 + tid]
         + fq.z * w2[(k + 2) * 128 + tid] + fq.w * w2[(k + 3) * 128 + tid];
  }
  float feat = fmaxf(acc, 0.0f);
  out[(size_t)(NB * 128) + (size_t)b * 128 + tid] = feat;
  float m = feat;
  for (int off = 32; off; off >>= 1) m = fmaxf(m, __shfl_xor(m, off));
  if (lane == 0) red[wv] = m;
  __syncthreads();
  m = fmaxf(red[0], red[1]);
  float e = expf(feat - m);
  float s = e;
  for (int off = 32; off; off >>= 1) s += __shfl_xor(s, off);
  __syncthreads();
  if (lane == 0) red[wv] = s;
  __syncthreads();
  s = red[0] + red[1];
  out[(size_t)b * 128 + tid] = e / s;
}

// ---------------------------------------------------------------------------
extern "C" void kernel_launch(void* const* d_in, const int* in_sizes, int n_in,
                              void* d_out, int out_size, void* d_ws, size_t ws_size,
                              hipStream_t stream) {
  const float* x    = (const float*)d_in[0];
  const float* adj  = (const float*)d_in[1];
  const float* wg1  = (const float*)d_in[2];
  const float* wsp1 = (const float*)d_in[3];
  const float* wg2  = (const float*)d_in[4];
  const float* wsp2 = (const float*)d_in[5];
  const float* l1w  = (const float*)d_in[6];
  const float* l1b  = (const float*)d_in[7];
  const float* l2w  = (const float*)d_in[8];
  const float* l2b  = (const float*)d_in[9];
  float* out = (float*)d_out;

  auto al = [](size_t v) { return (v + 255) & ~(size_t)255; };
  size_t oh1, ohp1, oadjp, oz, of;
  auto plan = [&](int g) -> size_t {
    size_t o = 0;
    oh1 = o;   o += al((size_t)g * NN0 * FD * 4);   // h1 (h2 overlay)
    ohp1 = o;  o += al((size_t)g * NN1 * FD * 4);
    oadjp = o; o += al((size_t)g * NN1 * 8);
    oz = o;    o += al((size_t)g * 8192 * 4);
    of = o;    o += al((size_t)g * FD * 4);
    return o;
  };
  int G = 2048;
  while (G > 64 && plan(G) > ws_size) G >>= 1;
  if (plan(G) > ws_size) return;

  char* wsb = (char*)d_ws;
  float* h1  = (float*)(wsb + oh1);
  float* hp1 = (float*)(wsb + ohp1);
  unsigned long long* adjp = (unsigned long long*)(wsb + oadjp);
  float* zbuf = (float*)(wsb + oz);
  float* fbuf = (float*)(wsb + of);

  const size_t LDS1 = (size_t)(NN0*112 + 2*NN0*64 + 448 + 224) * 4;     // 109,248
  const size_t LDS2 = (size_t)(NN0*FD + 448 + 112 + 112 + 56) * 4;      // 116,576
  const size_t LDS3 = (size_t)(NN1*FD + 2*NN1*64 + 112 + 64 + 64) * 4;  // 86,976
  const size_t LDS4 = (size_t)(NN1*FD + 112 + 64 + 64 + 32) * 4;        // 58,432

  for (int b0 = 0; b0 < NB; b0 += G) {
    k_stage1<<<G, 512, LDS1, stream>>>(x, adj, wg1, wsp1, h1, b0);
    k_pool1<<<G, 512, LDS2, stream>>>(h1, adj, hp1, adjp, zbuf, b0);
    k_stage2<<<G, 512, LDS3, stream>>>(hp1, adjp, wg2, wsp2, h1);
    k_pool2<<<G, 256, LDS4, stream>>>(h1, adjp, zbuf);
    k_lin1<<<dim3(G / 32, 4), 256, 0, stream>>>(zbuf, l1w, l1b, fbuf);
    k_head<<<G, 128, 0, stream>>>(fbuf, l2w, l2b, out, b0);
  }
}

// Round 4
// 6021.036 us; speedup vs baseline: 1.4572x; 1.0496x over previous
//
#include <hip/hip_runtime.h>
#include <hip/hip_bf16.h>

#define NB   2048
#define NN0  111
#define NN1  56
#define NN2  28
#define FD   256
#define HD   128

// ---------------------------------------------------------------------------
// K1: stage-1 conv. One block/graph, 512 thr = (col 0..63) x (wave 0..7).
// GEMM: xs broadcast b128 reads, 4 weight matrices at once (16 FMA / b128).
// Props: wave-uniform row, lane = col, pre-scaled buffers (pure adds).
// ---------------------------------------------------------------------------
__global__ __launch_bounds__(512) void k_stage1(
    const float* __restrict__ x, const float* __restrict__ adj,
    const float* __restrict__ wg, const float* __restrict__ wsp,
    float* __restrict__ h1, int b0)
{
  extern __shared__ float sm[];
  float* xs   = sm;                                // 111*112 = 12432
  float* bufA = xs + NN0 * 112;                    // 111*64 = 7104
  float* bufB = bufA + NN0 * 64;                   // 7104
  unsigned* abits = (unsigned*)(bufB + NN0 * 64);  // 448 u32
  float* dis0 = (float*)(abits + 448);             // 112
  float* dis1 = dis0 + 112;                        // 112

  const int tid  = threadIdx.x;
  const int lane = tid & 63;   // col
  const int wv   = tid >> 6;   // row group
  const int b    = b0 + blockIdx.x;
  const float* xb = x   + (size_t)b * (NN0 * NN0);
  const float* ab = adj + (size_t)b * (NN0 * NN0);

  for (int idx = tid; idx < NN0 * NN0; idx += 512) {
    int i = idx / NN0, k = idx - i * NN0;
    xs[i * 112 + k] = xb[idx];
  }
  for (int i = wv; i < NN0; i += 8) {
    unsigned long long m0 = __ballot(ab[i * NN0 + lane] != 0.0f);
    float a1v = (64 + lane < NN0) ? ab[i * NN0 + 64 + lane] : 0.0f;
    unsigned long long m1 = __ballot(a1v != 0.0f);
    if (lane == 0) {
      abits[i * 4 + 0] = (unsigned)m0; abits[i * 4 + 1] = (unsigned)(m0 >> 32);
      abits[i * 4 + 2] = (unsigned)m1; abits[i * 4 + 3] = (unsigned)(m1 >> 32);
      int d = __popcll(m0) + __popcll(m1);
      dis0[i] = (d > 0) ? (1.0f / sqrtf((float)d)) : 0.0f;
      dis1[i] = 1.0f / sqrtf((float)(d + 1));
    }
  }
  __syncthreads();

  auto nsum = [&](int i, const float* buf) {
    float acc = 0.0f;
    const unsigned* rb = abits + i * 4;
#pragma unroll
    for (int w4 = 0; w4 < 4; ++w4) {
      unsigned u = rb[w4];
      while (u) {
        int j = (w4 << 5) + __builtin_ctz(u); u &= u - 1;
        acc += buf[j * 64 + lane];
      }
    }
    return acc;
  };

  float* h1b = h1 + (size_t)blockIdx.x * (NN0 * FD);

  for (int c = 0; c < 2; ++c) {
    const int c0 = c * 64;
    float aG[14], a2[14], a1[14], a0v[14];
#pragma unroll
    for (int t = 0; t < 14; ++t) { aG[t] = 0.f; a2[t] = 0.f; a1[t] = 0.f; a0v[t] = 0.f; }
    const float* pG = wg  + c0 + lane;
    const float* p2 = wsp + 2 * (NN0 * HD) + c0 + lane;
    const float* p1 = wsp + 1 * (NN0 * HD) + c0 + lane;
    const float* p0 = wsp + c0 + lane;
    for (int kq = 0; kq < 27; ++kq) {
      int k0 = kq * 4;
      float g0 = pG[(k0+0)*HD], g1 = pG[(k0+1)*HD], g2 = pG[(k0+2)*HD], g3 = pG[(k0+3)*HD];
      float s0 = p2[(k0+0)*HD], s1 = p2[(k0+1)*HD], s2 = p2[(k0+2)*HD], s3 = p2[(k0+3)*HD];
      float u0 = p1[(k0+0)*HD], u1 = p1[(k0+1)*HD], u2 = p1[(k0+2)*HD], u3 = p1[(k0+3)*HD];
      float v0 = p0[(k0+0)*HD], v1 = p0[(k0+1)*HD], v2 = p0[(k0+2)*HD], v3 = p0[(k0+3)*HD];
#pragma unroll
      for (int t = 0; t < 14; ++t) {
        int r = wv + 8 * t;
        if (r < NN0) {
          float4 xq = *(const float4*)(xs + r * 112 + k0);
          aG[t]  += xq.x*g0 + xq.y*g1 + xq.z*g2 + xq.w*g3;
          a2[t]  += xq.x*s0 + xq.y*s1 + xq.z*s2 + xq.w*s3;
          a1[t]  += xq.x*u0 + xq.y*u1 + xq.z*u2 + xq.w*u3;
          a0v[t] += xq.x*v0 + xq.y*v1 + xq.z*v2 + xq.w*v3;
        }
      }
    }
#pragma unroll
    for (int k = 108; k < 111; ++k) {
      float gv = pG[k*HD], sv = p2[k*HD], uv = p1[k*HD], vv = p0[k*HD];
#pragma unroll
      for (int t = 0; t < 14; ++t) {
        int r = wv + 8 * t;
        if (r < NN0) {
          float xv = xs[r * 112 + k];
          aG[t] += xv * gv; a2[t] += xv * sv; a1[t] += xv * uv; a0v[t] += xv * vv;
        }
      }
    }

#pragma unroll
    for (int t = 0; t < 14; ++t) {
      int r = wv + 8 * t;
      if (r < NN0) bufA[r * 64 + lane] = dis1[r] * aG[t];
    }
    __syncthreads();
    for (int t = 0; t < 14; ++t) {
      int i = wv + 8 * t;
      if (i < NN0) {
        float acc = bufA[i * 64 + lane] + nsum(i, bufA);
        h1b[i * FD + c0 + lane] = fmaxf(dis1[i] * acc, 0.0f);
      }
    }
    __syncthreads();
#pragma unroll
    for (int t = 0; t < 14; ++t) {
      int r = wv + 8 * t;
      if (r < NN0) bufA[r * 64 + lane] = dis0[r] * a2[t];
    }
    __syncthreads();
    float cacc[14];
    for (int t = 0; t < 14; ++t) {
      int i = wv + 8 * t;
      if (i < NN0) {
        float s = nsum(i, bufA);
        bufB[i * 64 + lane] = -dis0[i] * dis0[i] * s;
        cacc[t] = -a2[t];
      } else cacc[t] = 0.f;
    }
    __syncthreads();
#pragma unroll
    for (int t = 0; t < 14; ++t) {
      int r = wv + 8 * t;
      if (r < NN0) bufA[r * 64 + lane] = dis0[r] * a1[t];
    }
    for (int t = 0; t < 14; ++t) {
      int i = wv + 8 * t;
      if (i < NN0) {
        float v = nsum(i, bufB);
        cacc[t] -= 2.0f * dis0[i] * v;
      }
    }
    __syncthreads();
    for (int t = 0; t < 14; ++t) {
      int i = wv + 8 * t;
      if (i < NN0) {
        float tl = nsum(i, bufA);
        float o = cacc[t] - dis0[i] * tl + a0v[t];
        h1b[i * FD + HD + c0 + lane] = fmaxf(o, 0.0f);
      }
    }
    __syncthreads();
  }
}

// ---------------------------------------------------------------------------
// K2: pool1 — exact f32 scores, stable top-56, gather, adjp, x1 readout
// ---------------------------------------------------------------------------
__global__ __launch_bounds__(512) void k_pool1(
    const float* __restrict__ h1, const float* __restrict__ adj,
    float* __restrict__ hp1, unsigned long long* __restrict__ adjp,
    float* __restrict__ zbuf, int b0)
{
  extern __shared__ float smemf[];
  float* hs = smemf;                               // 111*256
  unsigned* abits = (unsigned*)(hs + NN0 * FD);    // 448
  float* dinv = (float*)(abits + 448);             // 112
  float* sc = dinv + 112;                          // 112
  int* sel = (int*)(sc + 112);                     // 56

  const int tid = threadIdx.x, lane = tid & 63, wv = tid >> 6;
  const int bl = blockIdx.x;
  const int b = b0 + bl;
  const float* hb = h1 + (size_t)bl * (NN0 * FD);
  const float* ab = adj + (size_t)b * (NN0 * NN0);

  for (int q = tid; q < NN0 * 64; q += 512)
    ((float4*)hs)[q] = ((const float4*)hb)[q];
  for (int i = wv; i < NN0; i += 8) {
    unsigned long long m0 = __ballot(ab[i * NN0 + lane] != 0.0f);
    float a1v = (64 + lane < NN0) ? ab[i * NN0 + 64 + lane] : 0.0f;
    unsigned long long m1 = __ballot(a1v != 0.0f);
    if (lane == 0) {
      abits[i * 4 + 0] = (unsigned)m0; abits[i * 4 + 1] = (unsigned)(m0 >> 32);
      abits[i * 4 + 2] = (unsigned)m1; abits[i * 4 + 3] = (unsigned)(m1 >> 32);
      int d = __popcll(m0) + __popcll(m1);
      dinv[i] = (d > 0) ? (1.0f / (float)d) : 0.0f;
    }
  }
  __syncthreads();
  for (int i = wv; i < NN0; i += 8) {
    float nb0 = 0, nb1 = 0, nb2 = 0, nb3 = 0;
    const unsigned* rb = abits + i * 4;
#pragma unroll
    for (int w4 = 0; w4 < 4; ++w4) {
      unsigned u = rb[w4];
      while (u) {
        int j = (w4 << 5) + __builtin_ctz(u); u &= u - 1;
        const float* hr = hs + j * FD + lane;
        nb0 += hr[0]; nb1 += hr[64]; nb2 += hr[128]; nb3 += hr[192];
      }
    }
    const float* hi = hs + i * FD + lane;
    float di = dinv[i];
    float s = fabsf(hi[0] - di * nb0) + fabsf(hi[64] - di * nb1)
            + fabsf(hi[128] - di * nb2) + fabsf(hi[192] - di * nb3);
    for (int off = 32; off; off >>= 1) s += __shfl_xor(s, off);
    if (lane == 0) sc[i] = s;
  }
  __syncthreads();
  if (tid < NN0) {
    float my = sc[tid];
    int cnt = 0;
    for (int j = 0; j < NN0; ++j) {
      float sj = sc[j];
      cnt += (sj > my) || (sj == my && j < tid);
    }
    if (cnt < NN1) sel[cnt] = tid;
  }
  __syncthreads();
  float* hpb = hp1 + (size_t)bl * (NN1 * FD);
  for (int r = wv; r < NN1; r += 8) {
    int i = sel[r];
    const float* hr = hs + i * FD + lane;
    float* dst = hpb + r * FD + lane;
    dst[0] = hr[0]; dst[64] = hr[64]; dst[128] = hr[128]; dst[192] = hr[192];
    int j2 = (lane < NN1) ? sel[lane] : 0;
    bool bit = (lane < NN1) && ((abits[i * 4 + (j2 >> 5)] >> (j2 & 31)) & 1);
    unsigned long long m = __ballot(bit);
    if (lane == 0) adjp[(size_t)bl * NN1 + r] = m;
  }
  __syncthreads();
  float* zb = zbuf + (size_t)bl * 8192;
  if (tid < FD) {
    float mx = -3.402823466e38f, sm2 = 0.0f;
    for (int r = 0; r < NN1; ++r) {
      float v = hs[sel[r] * FD + tid];
      mx = fmaxf(mx, v); sm2 += v;
    }
    zb[7168 + tid] = mx;
    zb[7424 + tid] = sm2 / 56.0f;
  }
}

// ---------------------------------------------------------------------------
// K3: stage-2 conv (56 nodes, K=256), 4-matrix-sweep structure.
// ---------------------------------------------------------------------------
__global__ __launch_bounds__(512) void k_stage2(
    const float* __restrict__ hp1, const unsigned long long* __restrict__ adjp,
    const float* __restrict__ wg, const float* __restrict__ wsp,
    float* __restrict__ h2)
{
  extern __shared__ float sm[];
  float* hs   = sm;                                // 56*256 = 14336
  float* bufA = hs + NN1 * FD;                     // 3584
  float* bufB = bufA + NN1 * 64;                   // 3584
  unsigned long long* rowm = (unsigned long long*)(bufB + NN1 * 64); // 56
  float* dis0 = (float*)(rowm + 56);               // 64
  float* dis1 = dis0 + 64;                         // 64

  const int tid = threadIdx.x, lane = tid & 63, wv = tid >> 6;
  const int bl = blockIdx.x;
  const float* hb = hp1 + (size_t)bl * (NN1 * FD);
  for (int q = tid; q < NN1 * 64; q += 512)
    ((float4*)hs)[q] = ((const float4*)hb)[q];
  if (tid < NN1) {
    unsigned long long m = adjp[(size_t)bl * NN1 + tid];
    rowm[tid] = m;
    int d = __popcll(m);
    dis0[tid] = (d > 0) ? (1.0f / sqrtf((float)d)) : 0.0f;
    dis1[tid] = 1.0f / sqrtf((float)(d + 1));
  }
  __syncthreads();

  auto nsum = [&](int i, const float* buf) {
    float acc = 0.0f;
    unsigned long long u = rowm[i];
    while (u) {
      int j = __builtin_ctzll(u); u &= u - 1;
      acc += buf[j * 64 + lane];
    }
    return acc;
  };

  float* h2b = h2 + (size_t)bl * (NN1 * FD);

  for (int c = 0; c < 2; ++c) {
    const int c0 = c * 64;
    float aG[7], a2[7], a1[7], a0v[7];
#pragma unroll
    for (int t = 0; t < 7; ++t) { aG[t] = 0.f; a2[t] = 0.f; a1[t] = 0.f; a0v[t] = 0.f; }
    const float* pG = wg  + c0 + lane;
    const float* p2 = wsp + 2 * (FD * HD) + c0 + lane;
    const float* p1 = wsp + 1 * (FD * HD) + c0 + lane;
    const float* p0 = wsp + c0 + lane;
    for (int kq = 0; kq < 64; ++kq) {
      int k0 = kq * 4;
      float g0 = pG[(k0+0)*HD], g1 = pG[(k0+1)*HD], g2 = pG[(k0+2)*HD], g3 = pG[(k0+3)*HD];
      float s0 = p2[(k0+0)*HD], s1 = p2[(k0+1)*HD], s2 = p2[(k0+2)*HD], s3 = p2[(k0+3)*HD];
      float u0 = p1[(k0+0)*HD], u1 = p1[(k0+1)*HD], u2 = p1[(k0+2)*HD], u3 = p1[(k0+3)*HD];
      float v0 = p0[(k0+0)*HD], v1 = p0[(k0+1)*HD], v2 = p0[(k0+2)*HD], v3 = p0[(k0+3)*HD];
#pragma unroll
      for (int t = 0; t < 7; ++t) {
        int r = wv + 8 * t;
        float4 xq = *(const float4*)(hs + r * FD + k0);
        aG[t]  += xq.x*g0 + xq.y*g1 + xq.z*g2 + xq.w*g3;
        a2[t]  += xq.x*s0 + xq.y*s1 + xq.z*s2 + xq.w*s3;
        a1[t]  += xq.x*u0 + xq.y*u1 + xq.z*u2 + xq.w*u3;
        a0v[t] += xq.x*v0 + xq.y*v1 + xq.z*v2 + xq.w*v3;
      }
    }
#pragma unroll
    for (int t = 0; t < 7; ++t) bufA[(wv + 8*t) * 64 + lane] = dis1[wv + 8*t] * aG[t];
    __syncthreads();
#pragma unroll
    for (int t = 0; t < 7; ++t) {
      int i = wv + 8 * t;
      float acc = bufA[i * 64 + lane] + nsum(i, bufA);
      h2b[i * FD + c0 + lane] = fmaxf(dis1[i] * acc, 0.0f);
    }
    __syncthreads();
#pragma unroll
    for (int t = 0; t < 7; ++t) bufA[(wv + 8*t) * 64 + lane] = dis0[wv + 8*t] * a2[t];
    __syncthreads();
    float cacc[7];
#pragma unroll
    for (int t = 0; t < 7; ++t) {
      int i = wv + 8 * t;
      float s = nsum(i, bufA);
      bufB[i * 64 + lane] = -dis0[i] * dis0[i] * s;
      cacc[t] = -a2[t];
    }
    __syncthreads();
#pragma unroll
    for (int t = 0; t < 7; ++t) bufA[(wv + 8*t) * 64 + lane] = dis0[wv + 8*t] * a1[t];
#pragma unroll
    for (int t = 0; t < 7; ++t) {
      int i = wv + 8 * t;
      float v = nsum(i, bufB);
      cacc[t] -= 2.0f * dis0[i] * v;
    }
    __syncthreads();
#pragma unroll
    for (int t = 0; t < 7; ++t) {
      int i = wv + 8 * t;
      float tl = nsum(i, bufA);
      float o = cacc[t] - dis0[i] * tl + a0v[t];
      h2b[i * FD + HD + c0 + lane] = fmaxf(o, 0.0f);
    }
    __syncthreads();
  }
}

// ---------------------------------------------------------------------------
// K4: pool2 + readout; flat h -> zbuf[0..7167], x2 -> zbuf[7680..]
// ---------------------------------------------------------------------------
__global__ __launch_bounds__(256) void k_pool2(
    const float* __restrict__ h2, const unsigned long long* __restrict__ adjp,
    float* __restrict__ zbuf)
{
  extern __shared__ float smemf[];
  float* hs = smemf;                                        // 56*256
  unsigned long long* rowm = (unsigned long long*)(hs + NN1 * FD);
  float* dinv = (float*)(rowm + 56);
  float* sc = dinv + 64;
  int* sel = (int*)(sc + 64);

  const int tid = threadIdx.x, lane = tid & 63, wv = tid >> 6;
  const int bl = blockIdx.x;
  const float* hb = h2 + (size_t)bl * (NN1 * FD);
  for (int q = tid; q < NN1 * 64; q += 256)
    ((float4*)hs)[q] = ((const float4*)hb)[q];
  if (tid < NN1) {
    unsigned long long m = adjp[(size_t)bl * NN1 + tid];
    rowm[tid] = m;
    int d = __popcll(m);
    dinv[tid] = (d > 0) ? (1.0f / (float)d) : 0.0f;
  }
  __syncthreads();
  for (int i = wv; i < NN1; i += 4) {
    float nb0 = 0, nb1 = 0, nb2 = 0, nb3 = 0;
    unsigned long long u = rowm[i];
    while (u) {
      int j = __builtin_ctzll(u); u &= u - 1;
      const float* hr = hs + j * FD + lane;
      nb0 += hr[0]; nb1 += hr[64]; nb2 += hr[128]; nb3 += hr[192];
    }
    const float* hi = hs + i * FD + lane;
    float di = dinv[i];
    float s = fabsf(hi[0] - di * nb0) + fabsf(hi[64] - di * nb1)
            + fabsf(hi[128] - di * nb2) + fabsf(hi[192] - di * nb3);
    for (int off = 32; off; off >>= 1) s += __shfl_xor(s, off);
    if (lane == 0) sc[i] = s;
  }
  __syncthreads();
  if (tid < NN1) {
    float my = sc[tid];
    int cnt = 0;
    for (int j = 0; j < NN1; ++j) {
      float sj = sc[j];
      cnt += (sj > my) || (sj == my && j < tid);
    }
    if (cnt < NN2) sel[cnt] = tid;
  }
  __syncthreads();
  float* zb = zbuf + (size_t)bl * 8192;
  for (int r = wv; r < NN2; r += 4) {
    const float* hr = hs + sel[r] * FD + lane;
    float* dst = zb + r * FD + lane;
    dst[0] = hr[0]; dst[64] = hr[64]; dst[128] = hr[128]; dst[192] = hr[192];
  }
  {
    float mx = -3.402823466e38f, sm2 = 0.0f;
    for (int r = 0; r < NN2; ++r) {
      float v = hs[sel[r] * FD + tid];
      mx = fmaxf(mx, v); sm2 += v;
    }
    zb[7680 + tid] = mx;
    zb[7936 + tid] = sm2 / 28.0f;
  }
}

// ---------------------------------------------------------------------------
// K5a: split-K GEMM partial. grid (G/64, 4, 8), 256 thr.
// Tile 64x64, BK=32, thread tile 4x4; zt[k][m] stride 66, wt[k][n] stride 68.
// Register prefetch of next K-block hides global latency.
// ---------------------------------------------------------------------------
__global__ __launch_bounds__(256, 4) void k_lin1p(
    const float* __restrict__ zbuf, const float* __restrict__ w,
    float* __restrict__ part, int G)
{
  __shared__ float zt[32][66];
  __shared__ float wt[32][68];
  const int tid = threadIdx.x;
  const int g0 = blockIdx.x * 64;
  const int n0 = blockIdx.y * 64;
  const int kb = blockIdx.z * 1024;
  const int cg = tid & 15;   // 4-col group
  const int rg = tid >> 4;   // 4-row group
  const int sk = tid & 31, sm = tid >> 5;   // z staging
  const int wn = tid & 63, wk = tid >> 6;   // w staging

  float acc[4][4];
#pragma unroll
  for (int i = 0; i < 4; ++i)
#pragma unroll
    for (int j = 0; j < 4; ++j) acc[i][j] = 0.f;

  const float* zp = zbuf + (size_t)g0 * 8192 + kb;
  const float* wp = w + (size_t)kb * 256 + n0;

  float zr[8], wr[8];
#pragma unroll
  for (int q = 0; q < 8; ++q) zr[q] = zp[(size_t)(sm + 8*q) * 8192 + sk];
#pragma unroll
  for (int q = 0; q < 8; ++q) wr[q] = wp[(size_t)(wk + 4*q) * 256 + wn];
#pragma unroll
  for (int q = 0; q < 8; ++q) zt[sk][sm + 8*q] = zr[q];
#pragma unroll
  for (int q = 0; q < 8; ++q) wt[wk + 4*q][wn] = wr[q];
  __syncthreads();

  for (int it = 0; it < 32; ++it) {
    if (it + 1 < 32) {
      const float* zn = zp + (it + 1) * 32;
      const float* wn2 = wp + (size_t)(it + 1) * 32 * 256;
#pragma unroll
      for (int q = 0; q < 8; ++q) zr[q] = zn[(size_t)(sm + 8*q) * 8192 + sk];
#pragma unroll
      for (int q = 0; q < 8; ++q) wr[q] = wn2[(size_t)(wk + 4*q) * 256 + wn];
    }
#pragma unroll
    for (int k = 0; k < 32; ++k) {
      float2 za = *(const float2*)&zt[k][rg * 4];
      float2 zb2 = *(const float2*)&zt[k][rg * 4 + 2];
      float4 wv = *(const float4*)&wt[k][cg * 4];
      acc[0][0] += za.x * wv.x; acc[0][1] += za.x * wv.y;
      acc[0][2] += za.x * wv.z; acc[0][3] += za.x * wv.w;
      acc[1][0] += za.y * wv.x; acc[1][1] += za.y * wv.y;
      acc[1][2] += za.y * wv.z; acc[1][3] += za.y * wv.w;
      acc[2][0] += zb2.x * wv.x; acc[2][1] += zb2.x * wv.y;
      acc[2][2] += zb2.x * wv.z; acc[2][3] += zb2.x * wv.w;
      acc[3][0] += zb2.y * wv.x; acc[3][1] += zb2.y * wv.y;
      acc[3][2] += zb2.y * wv.z; acc[3][3] += zb2.y * wv.w;
    }
    __syncthreads();
    if (it + 1 < 32) {
#pragma unroll
      for (int q = 0; q < 8; ++q) zt[sk][sm + 8*q] = zr[q];
#pragma unroll
      for (int q = 0; q < 8; ++q) wt[wk + 4*q][wn] = wr[q];
      __syncthreads();
    }
  }

  float* pb = part + (size_t)blockIdx.z * G * 256 + (size_t)g0 * 256 + n0;
#pragma unroll
  for (int i = 0; i < 4; ++i) {
    float4 v = make_float4(acc[i][0], acc[i][1], acc[i][2], acc[i][3]);
    *(float4*)&pb[(size_t)(rg * 4 + i) * 256 + cg * 4] = v;
  }
}

// ---------------------------------------------------------------------------
// K5b: reduce 8 partials + bias + relu -> fbuf. Deterministic fixed order.
// ---------------------------------------------------------------------------
__global__ __launch_bounds__(256) void k_lin1r(
    const float* __restrict__ part, const float* __restrict__ bias,
    float* __restrict__ fbuf, int G)
{
  int idx = blockIdx.x * 256 + threadIdx.x;   // float4 index
  int n4 = idx & 63, g = idx >> 6;
  const float* p = part + (size_t)g * 256 + n4 * 4;
  size_t stride = (size_t)G * 256;
  float4 s = *(const float4*)p;
#pragma unroll
  for (int z = 1; z < 8; ++z) {
    float4 v = *(const float4*)(p + (size_t)z * stride);
    s.x += v.x; s.y += v.y; s.z += v.z; s.w += v.w;
  }
  float4 bv = *(const float4*)(bias + n4 * 4);
  s.x = fmaxf(s.x + bv.x, 0.f); s.y = fmaxf(s.y + bv.y, 0.f);
  s.z = fmaxf(s.z + bv.z, 0.f); s.w = fmaxf(s.w + bv.w, 0.f);
  *(float4*)(fbuf + (size_t)g * 256 + n4 * 4) = s;
}

// ---------------------------------------------------------------------------
// K6: features = relu(f @ lin2_w + b2); x_lo = softmax(features)
// ---------------------------------------------------------------------------
__global__ __launch_bounds__(128) void k_head(
    const float* __restrict__ fbuf, const float* __restrict__ w2,
    const float* __restrict__ b2, float* __restrict__ out, int b0)
{
  __shared__ __align__(16) float fs[256];
  __shared__ float red[2];
  const int tid = threadIdx.x, lane = tid & 63, wv = tid >> 6;
  const int bl = blockIdx.x, b = b0 + bl;
  for (int i = tid; i < 256; i += 128) fs[i] = fbuf[(size_t)bl * 256 + i];
  __syncthreads();
  float acc = b2[tid];
  for (int k = 0; k < 256; k += 4) {
    float4 fq = *(const float4*)(fs + k);
    acc += fq.x * w2[(k + 0) * 128 + tid] + fq.y * w2[(k + 1) * 128 + tid]
         + fq.z * w2[(k + 2) * 128 + tid] + fq.w * w2[(k + 3) * 128 + tid];
  }
  float feat = fmaxf(acc, 0.0f);
  out[(size_t)(NB * 128) + (size_t)b * 128 + tid] = feat;
  float m = feat;
  for (int off = 32; off; off >>= 1) m = fmaxf(m, __shfl_xor(m, off));
  if (lane == 0) red[wv] = m;
  __syncthreads();
  m = fmaxf(red[0], red[1]);
  float e = expf(feat - m);
  float s = e;
  for (int off = 32; off; off >>= 1) s += __shfl_xor(s, off);
  __syncthreads();
  if (lane == 0) red[wv] = s;
  __syncthreads();
  s = red[0] + red[1];
  out[(size_t)b * 128 + tid] = e / s;
}

// ---------------------------------------------------------------------------
extern "C" void kernel_launch(void* const* d_in, const int* in_sizes, int n_in,
                              void* d_out, int out_size, void* d_ws, size_t ws_size,
                              hipStream_t stream) {
  const float* x    = (const float*)d_in[0];
  const float* adj  = (const float*)d_in[1];
  const float* wg1  = (const float*)d_in[2];
  const float* wsp1 = (const float*)d_in[3];
  const float* wg2  = (const float*)d_in[4];
  const float* wsp2 = (const float*)d_in[5];
  const float* l1w  = (const float*)d_in[6];
  const float* l1b  = (const float*)d_in[7];
  const float* l2w  = (const float*)d_in[8];
  const float* l2b  = (const float*)d_in[9];
  float* out = (float*)d_out;

  auto al = [](size_t v) { return (v + 255) & ~(size_t)255; };
  size_t oh1, ohp1, oadjp, oz, opart, of;
  auto plan = [&](int g) -> size_t {
    size_t o = 0;
    oh1 = o;   o += al((size_t)g * NN0 * FD * 4);   // h1 (h2 overlay)
    ohp1 = o;  o += al((size_t)g * NN1 * FD * 4);
    oadjp = o; o += al((size_t)g * NN1 * 8);
    oz = o;    o += al((size_t)g * 8192 * 4);
    opart = o; o += al((size_t)g * 256 * 8 * 4);    // 8 split-K partials
    of = o;    o += al((size_t)g * FD * 4);
    return o;
  };
  int G = 2048;
  while (G > 64 && plan(G) > ws_size) G >>= 1;
  if (plan(G) > ws_size) return;

  char* wsb = (char*)d_ws;
  float* h1  = (float*)(wsb + oh1);
  float* hp1 = (float*)(wsb + ohp1);
  unsigned long long* adjp = (unsigned long long*)(wsb + oadjp);
  float* zbuf = (float*)(wsb + oz);
  float* part = (float*)(wsb + opart);
  float* fbuf = (float*)(wsb + of);

  const size_t LDS1 = (size_t)(NN0*112 + 2*NN0*64 + 448 + 224) * 4;     // 109,248
  const size_t LDS2 = (size_t)(NN0*FD + 448 + 112 + 112 + 56) * 4;      // 116,576
  const size_t LDS3 = (size_t)(NN1*FD + 2*NN1*64 + 112 + 64 + 64) * 4;  // 86,976
  const size_t LDS4 = (size_t)(NN1*FD + 112 + 64 + 64 + 32) * 4;        // 58,432

  for (int b0 = 0; b0 < NB; b0 += G) {
    k_stage1<<<G, 512, LDS1, stream>>>(x, adj, wg1, wsp1, h1, b0);
    k_pool1<<<G, 512, LDS2, stream>>>(h1, adj, hp1, adjp, zbuf, b0);
    k_stage2<<<G, 512, LDS3, stream>>>(hp1, adjp, wg2, wsp2, h1);
    k_pool2<<<G, 256, LDS4, stream>>>(h1, adjp, zbuf);
    k_lin1p<<<dim3(G / 64, 4, 8), 256, 0, stream>>>(zbuf, l1w, part, G);
    k_lin1r<<<G / 4, 256, 0, stream>>>(part, l1b, fbuf, G);
    k_head<<<G, 128, 0, stream>>>(fbuf, l2w, l2b, out, b0);
  }
}

// Round 5
// 4808.871 us; speedup vs baseline: 1.8245x; 1.2521x over previous
//
#include <hip/hip_runtime.h>
#include <hip/hip_bf16.h>

#define NB   2048
#define NN0  111
#define NN1  56
#define NN2  28
#define FD   256
#define HD   128

// ---------------------------------------------------------------------------
// K1: stage-1 conv. One block/graph, 512 thr = (col 0..63) x (wave 0..7).
// GEMM: xs broadcast b128 reads, 4 weight matrices at once (16 FMA / b128).
// Props: wave-uniform row, lane = col, scalarized bitmask walk.
// ---------------------------------------------------------------------------
__global__ __launch_bounds__(512) void k_stage1(
    const float* __restrict__ x, const float* __restrict__ adj,
    const float* __restrict__ wg, const float* __restrict__ wsp,
    float* __restrict__ h1, int b0)
{
  extern __shared__ float sm[];
  float* xs   = sm;                                // 111*112 = 12432
  float* bufA = xs + NN0 * 112;                    // 111*64 = 7104
  float* bufB = bufA + NN0 * 64;                   // 7104
  unsigned* abits = (unsigned*)(bufB + NN0 * 64);  // 448 u32
  float* dis0 = (float*)(abits + 448);             // 112
  float* dis1 = dis0 + 112;                        // 112

  const int tid  = threadIdx.x;
  const int lane = tid & 63;   // col
  const int wv   = tid >> 6;   // row group
  const int b    = b0 + blockIdx.x;
  const float* xb = x   + (size_t)b * (NN0 * NN0);
  const float* ab = adj + (size_t)b * (NN0 * NN0);

  for (int idx = tid; idx < NN0 * NN0; idx += 512) {
    int i = idx / NN0, k = idx - i * NN0;
    xs[i * 112 + k] = xb[idx];
  }
  for (int i = wv; i < NN0; i += 8) {
    unsigned long long m0 = __ballot(ab[i * NN0 + lane] != 0.0f);
    float a1v = (64 + lane < NN0) ? ab[i * NN0 + 64 + lane] : 0.0f;
    unsigned long long m1 = __ballot(a1v != 0.0f);
    if (lane == 0) {
      abits[i * 4 + 0] = (unsigned)m0; abits[i * 4 + 1] = (unsigned)(m0 >> 32);
      abits[i * 4 + 2] = (unsigned)m1; abits[i * 4 + 3] = (unsigned)(m1 >> 32);
      int d = __popcll(m0) + __popcll(m1);
      dis0[i] = (d > 0) ? (1.0f / sqrtf((float)d)) : 0.0f;
      dis1[i] = 1.0f / sqrtf((float)(d + 1));
    }
  }
  __syncthreads();

  // neighbor sum; i is wave-uniform -> scalarize mask walk
  auto nsum = [&](int i, const float* buf) {
    float acc = 0.0f;
    const unsigned* rb = abits + i * 4;
#pragma unroll
    for (int w4 = 0; w4 < 4; ++w4) {
      unsigned u = __builtin_amdgcn_readfirstlane(rb[w4]);
      while (u) {
        int j = (w4 << 5) + __builtin_ctz(u); u &= u - 1;
        acc += buf[j * 64 + lane];
      }
    }
    return acc;
  };

  float* h1b = h1 + (size_t)blockIdx.x * (NN0 * FD);

  for (int c = 0; c < 2; ++c) {
    const int c0 = c * 64;
    float aG[14], a2[14], a1[14], a0v[14];
#pragma unroll
    for (int t = 0; t < 14; ++t) { aG[t] = 0.f; a2[t] = 0.f; a1[t] = 0.f; a0v[t] = 0.f; }
    const float* pG = wg  + c0 + lane;
    const float* p2 = wsp + 2 * (NN0 * HD) + c0 + lane;
    const float* p1 = wsp + 1 * (NN0 * HD) + c0 + lane;
    const float* p0 = wsp + c0 + lane;
    for (int kq = 0; kq < 27; ++kq) {
      int k0 = kq * 4;
      float g0 = pG[(k0+0)*HD], g1 = pG[(k0+1)*HD], g2 = pG[(k0+2)*HD], g3 = pG[(k0+3)*HD];
      float s0 = p2[(k0+0)*HD], s1 = p2[(k0+1)*HD], s2 = p2[(k0+2)*HD], s3 = p2[(k0+3)*HD];
      float u0 = p1[(k0+0)*HD], u1 = p1[(k0+1)*HD], u2 = p1[(k0+2)*HD], u3 = p1[(k0+3)*HD];
      float v0 = p0[(k0+0)*HD], v1 = p0[(k0+1)*HD], v2 = p0[(k0+2)*HD], v3 = p0[(k0+3)*HD];
#pragma unroll
      for (int t = 0; t < 14; ++t) {
        int r = wv + 8 * t;
        if (r < NN0) {
          float4 xq = *(const float4*)(xs + r * 112 + k0);
          aG[t]  += xq.x*g0 + xq.y*g1 + xq.z*g2 + xq.w*g3;
          a2[t]  += xq.x*s0 + xq.y*s1 + xq.z*s2 + xq.w*s3;
          a1[t]  += xq.x*u0 + xq.y*u1 + xq.z*u2 + xq.w*u3;
          a0v[t] += xq.x*v0 + xq.y*v1 + xq.z*v2 + xq.w*v3;
        }
      }
    }
#pragma unroll
    for (int k = 108; k < 111; ++k) {
      float gv = pG[k*HD], sv = p2[k*HD], uv = p1[k*HD], vv = p0[k*HD];
#pragma unroll
      for (int t = 0; t < 14; ++t) {
        int r = wv + 8 * t;
        if (r < NN0) {
          float xv = xs[r * 112 + k];
          aG[t] += xv * gv; a2[t] += xv * sv; a1[t] += xv * uv; a0v[t] += xv * vv;
        }
      }
    }

#pragma unroll
    for (int t = 0; t < 14; ++t) {
      int r = wv + 8 * t;
      if (r < NN0) bufA[r * 64 + lane] = dis1[r] * aG[t];
    }
    __syncthreads();
    for (int t = 0; t < 14; ++t) {
      int i = wv + 8 * t;
      if (i < NN0) {
        float acc = bufA[i * 64 + lane] + nsum(i, bufA);
        h1b[i * FD + c0 + lane] = fmaxf(dis1[i] * acc, 0.0f);
      }
    }
    __syncthreads();
#pragma unroll
    for (int t = 0; t < 14; ++t) {
      int r = wv + 8 * t;
      if (r < NN0) bufA[r * 64 + lane] = dis0[r] * a2[t];
    }
    __syncthreads();
    float cacc[14];
    for (int t = 0; t < 14; ++t) {
      int i = wv + 8 * t;
      if (i < NN0) {
        float s = nsum(i, bufA);
        bufB[i * 64 + lane] = -dis0[i] * dis0[i] * s;
        cacc[t] = -a2[t];
      } else cacc[t] = 0.f;
    }
    __syncthreads();
#pragma unroll
    for (int t = 0; t < 14; ++t) {
      int r = wv + 8 * t;
      if (r < NN0) bufA[r * 64 + lane] = dis0[r] * a1[t];
    }
    for (int t = 0; t < 14; ++t) {
      int i = wv + 8 * t;
      if (i < NN0) {
        float v = nsum(i, bufB);
        cacc[t] -= 2.0f * dis0[i] * v;
      }
    }
    __syncthreads();
    for (int t = 0; t < 14; ++t) {
      int i = wv + 8 * t;
      if (i < NN0) {
        float tl = nsum(i, bufA);
        float o = cacc[t] - dis0[i] * tl + a0v[t];
        h1b[i * FD + HD + c0 + lane] = fmaxf(o, 0.0f);
      }
    }
    __syncthreads();
  }
}

// ---------------------------------------------------------------------------
// K2: pool1 — exact f32 scores, stable top-56, gather, adjp, x1 readout
// ---------------------------------------------------------------------------
__global__ __launch_bounds__(512) void k_pool1(
    const float* __restrict__ h1, const float* __restrict__ adj,
    float* __restrict__ hp1, unsigned long long* __restrict__ adjp,
    float* __restrict__ zbuf, int b0)
{
  extern __shared__ float smemf[];
  float* hs = smemf;                               // 111*256
  unsigned* abits = (unsigned*)(hs + NN0 * FD);    // 448
  float* dinv = (float*)(abits + 448);             // 112
  float* sc = dinv + 112;                          // 112
  int* sel = (int*)(sc + 112);                     // 56

  const int tid = threadIdx.x, lane = tid & 63, wv = tid >> 6;
  const int bl = blockIdx.x;
  const int b = b0 + bl;
  const float* hb = h1 + (size_t)bl * (NN0 * FD);
  const float* ab = adj + (size_t)b * (NN0 * NN0);

  for (int q = tid; q < NN0 * 64; q += 512)
    ((float4*)hs)[q] = ((const float4*)hb)[q];
  for (int i = wv; i < NN0; i += 8) {
    unsigned long long m0 = __ballot(ab[i * NN0 + lane] != 0.0f);
    float a1v = (64 + lane < NN0) ? ab[i * NN0 + 64 + lane] : 0.0f;
    unsigned long long m1 = __ballot(a1v != 0.0f);
    if (lane == 0) {
      abits[i * 4 + 0] = (unsigned)m0; abits[i * 4 + 1] = (unsigned)(m0 >> 32);
      abits[i * 4 + 2] = (unsigned)m1; abits[i * 4 + 3] = (unsigned)(m1 >> 32);
      int d = __popcll(m0) + __popcll(m1);
      dinv[i] = (d > 0) ? (1.0f / (float)d) : 0.0f;
    }
  }
  __syncthreads();
  for (int i = wv; i < NN0; i += 8) {
    float nb0 = 0, nb1 = 0, nb2 = 0, nb3 = 0;
    const unsigned* rb = abits + i * 4;
#pragma unroll
    for (int w4 = 0; w4 < 4; ++w4) {
      unsigned u = __builtin_amdgcn_readfirstlane(rb[w4]);
      while (u) {
        int j = (w4 << 5) + __builtin_ctz(u); u &= u - 1;
        const float* hr = hs + j * FD + lane;
        nb0 += hr[0]; nb1 += hr[64]; nb2 += hr[128]; nb3 += hr[192];
      }
    }
    const float* hi = hs + i * FD + lane;
    float di = dinv[i];
    float s = fabsf(hi[0] - di * nb0) + fabsf(hi[64] - di * nb1)
            + fabsf(hi[128] - di * nb2) + fabsf(hi[192] - di * nb3);
    for (int off = 32; off; off >>= 1) s += __shfl_xor(s, off);
    if (lane == 0) sc[i] = s;
  }
  __syncthreads();
  if (tid < NN0) {
    float my = sc[tid];
    int cnt = 0;
    for (int j = 0; j < NN0; ++j) {
      float sj = sc[j];
      cnt += (sj > my) || (sj == my && j < tid);
    }
    if (cnt < NN1) sel[cnt] = tid;
  }
  __syncthreads();
  float* hpb = hp1 + (size_t)bl * (NN1 * FD);
  for (int r = wv; r < NN1; r += 8) {
    int i = sel[r];
    const float* hr = hs + i * FD + lane;
    float* dst = hpb + r * FD + lane;
    dst[0] = hr[0]; dst[64] = hr[64]; dst[128] = hr[128]; dst[192] = hr[192];
    int j2 = (lane < NN1) ? sel[lane] : 0;
    bool bit = (lane < NN1) && ((abits[i * 4 + (j2 >> 5)] >> (j2 & 31)) & 1);
    unsigned long long m = __ballot(bit);
    if (lane == 0) adjp[(size_t)bl * NN1 + r] = m;
  }
  __syncthreads();
  float* zb = zbuf + (size_t)bl * 8192;
  if (tid < FD) {
    float mx = -3.402823466e38f, sm2 = 0.0f;
    for (int r = 0; r < NN1; ++r) {
      float v = hs[sel[r] * FD + tid];
      mx = fmaxf(mx, v); sm2 += v;
    }
    zb[7168 + tid] = mx;
    zb[7424 + tid] = sm2 / 56.0f;
  }
}

// ---------------------------------------------------------------------------
// K3: stage-2 conv (56 nodes, K=256), 4-matrix-sweep structure.
// ---------------------------------------------------------------------------
__global__ __launch_bounds__(512) void k_stage2(
    const float* __restrict__ hp1, const unsigned long long* __restrict__ adjp,
    const float* __restrict__ wg, const float* __restrict__ wsp,
    float* __restrict__ h2)
{
  extern __shared__ float sm[];
  float* hs   = sm;                                // 56*256 = 14336
  float* bufA = hs + NN1 * FD;                     // 3584
  float* bufB = bufA + NN1 * 64;                   // 3584
  unsigned long long* rowm = (unsigned long long*)(bufB + NN1 * 64); // 56
  float* dis0 = (float*)(rowm + 56);               // 64
  float* dis1 = dis0 + 64;                         // 64

  const int tid = threadIdx.x, lane = tid & 63, wv = tid >> 6;
  const int bl = blockIdx.x;
  const float* hb = hp1 + (size_t)bl * (NN1 * FD);
  for (int q = tid; q < NN1 * 64; q += 512)
    ((float4*)hs)[q] = ((const float4*)hb)[q];
  if (tid < NN1) {
    unsigned long long m = adjp[(size_t)bl * NN1 + tid];
    rowm[tid] = m;
    int d = __popcll(m);
    dis0[tid] = (d > 0) ? (1.0f / sqrtf((float)d)) : 0.0f;
    dis1[tid] = 1.0f / sqrtf((float)(d + 1));
  }
  __syncthreads();

  auto nsum = [&](int i, const float* buf) {
    float acc = 0.0f;
    unsigned long long m = ((const unsigned long long*)rowm)[i];
    unsigned ulo = __builtin_amdgcn_readfirstlane((unsigned)m);
    unsigned uhi = __builtin_amdgcn_readfirstlane((unsigned)(m >> 32));
    while (ulo) {
      int j = __builtin_ctz(ulo); ulo &= ulo - 1;
      acc += buf[j * 64 + lane];
    }
    while (uhi) {
      int j = 32 + __builtin_ctz(uhi); uhi &= uhi - 1;
      acc += buf[j * 64 + lane];
    }
    return acc;
  };

  float* h2b = h2 + (size_t)bl * (NN1 * FD);

  for (int c = 0; c < 2; ++c) {
    const int c0 = c * 64;
    float aG[7], a2[7], a1[7], a0v[7];
#pragma unroll
    for (int t = 0; t < 7; ++t) { aG[t] = 0.f; a2[t] = 0.f; a1[t] = 0.f; a0v[t] = 0.f; }
    const float* pG = wg  + c0 + lane;
    const float* p2 = wsp + 2 * (FD * HD) + c0 + lane;
    const float* p1 = wsp + 1 * (FD * HD) + c0 + lane;
    const float* p0 = wsp + c0 + lane;
    for (int kq = 0; kq < 64; ++kq) {
      int k0 = kq * 4;
      float g0 = pG[(k0+0)*HD], g1 = pG[(k0+1)*HD], g2 = pG[(k0+2)*HD], g3 = pG[(k0+3)*HD];
      float s0 = p2[(k0+0)*HD], s1 = p2[(k0+1)*HD], s2 = p2[(k0+2)*HD], s3 = p2[(k0+3)*HD];
      float u0 = p1[(k0+0)*HD], u1 = p1[(k0+1)*HD], u2 = p1[(k0+2)*HD], u3 = p1[(k0+3)*HD];
      float v0 = p0[(k0+0)*HD], v1 = p0[(k0+1)*HD], v2 = p0[(k0+2)*HD], v3 = p0[(k0+3)*HD];
#pragma unroll
      for (int t = 0; t < 7; ++t) {
        int r = wv + 8 * t;
        float4 xq = *(const float4*)(hs + r * FD + k0);
        aG[t]  += xq.x*g0 + xq.y*g1 + xq.z*g2 + xq.w*g3;
        a2[t]  += xq.x*s0 + xq.y*s1 + xq.z*s2 + xq.w*s3;
        a1[t]  += xq.x*u0 + xq.y*u1 + xq.z*u2 + xq.w*u3;
        a0v[t] += xq.x*v0 + xq.y*v1 + xq.z*v2 + xq.w*v3;
      }
    }
#pragma unroll
    for (int t = 0; t < 7; ++t) bufA[(wv + 8*t) * 64 + lane] = dis1[wv + 8*t] * aG[t];
    __syncthreads();
#pragma unroll
    for (int t = 0; t < 7; ++t) {
      int i = wv + 8 * t;
      float acc = bufA[i * 64 + lane] + nsum(i, bufA);
      h2b[i * FD + c0 + lane] = fmaxf(dis1[i] * acc, 0.0f);
    }
    __syncthreads();
#pragma unroll
    for (int t = 0; t < 7; ++t) bufA[(wv + 8*t) * 64 + lane] = dis0[wv + 8*t] * a2[t];
    __syncthreads();
    float cacc[7];
#pragma unroll
    for (int t = 0; t < 7; ++t) {
      int i = wv + 8 * t;
      float s = nsum(i, bufA);
      bufB[i * 64 + lane] = -dis0[i] * dis0[i] * s;
      cacc[t] = -a2[t];
    }
    __syncthreads();
#pragma unroll
    for (int t = 0; t < 7; ++t) bufA[(wv + 8*t) * 64 + lane] = dis0[wv + 8*t] * a1[t];
#pragma unroll
    for (int t = 0; t < 7; ++t) {
      int i = wv + 8 * t;
      float v = nsum(i, bufB);
      cacc[t] -= 2.0f * dis0[i] * v;
    }
    __syncthreads();
#pragma unroll
    for (int t = 0; t < 7; ++t) {
      int i = wv + 8 * t;
      float tl = nsum(i, bufA);
      float o = cacc[t] - dis0[i] * tl + a0v[t];
      h2b[i * FD + HD + c0 + lane] = fmaxf(o, 0.0f);
    }
    __syncthreads();
  }
}

// ---------------------------------------------------------------------------
// K4: pool2 + readout; flat h -> zbuf[0..7167], x2 -> zbuf[7680..]
// ---------------------------------------------------------------------------
__global__ __launch_bounds__(256) void k_pool2(
    const float* __restrict__ h2, const unsigned long long* __restrict__ adjp,
    float* __restrict__ zbuf)
{
  extern __shared__ float smemf[];
  float* hs = smemf;                                        // 56*256
  unsigned long long* rowm = (unsigned long long*)(hs + NN1 * FD);
  float* dinv = (float*)(rowm + 56);
  float* sc = dinv + 64;
  int* sel = (int*)(sc + 64);

  const int tid = threadIdx.x, lane = tid & 63, wv = tid >> 6;
  const int bl = blockIdx.x;
  const float* hb = h2 + (size_t)bl * (NN1 * FD);
  for (int q = tid; q < NN1 * 64; q += 256)
    ((float4*)hs)[q] = ((const float4*)hb)[q];
  if (tid < NN1) {
    unsigned long long m = adjp[(size_t)bl * NN1 + tid];
    rowm[tid] = m;
    int d = __popcll(m);
    dinv[tid] = (d > 0) ? (1.0f / (float)d) : 0.0f;
  }
  __syncthreads();
  for (int i = wv; i < NN1; i += 4) {
    float nb0 = 0, nb1 = 0, nb2 = 0, nb3 = 0;
    unsigned long long m = rowm[i];
    unsigned ulo = __builtin_amdgcn_readfirstlane((unsigned)m);
    unsigned uhi = __builtin_amdgcn_readfirstlane((unsigned)(m >> 32));
    while (ulo) {
      int j = __builtin_ctz(ulo); ulo &= ulo - 1;
      const float* hr = hs + j * FD + lane;
      nb0 += hr[0]; nb1 += hr[64]; nb2 += hr[128]; nb3 += hr[192];
    }
    while (uhi) {
      int j = 32 + __builtin_ctz(uhi); uhi &= uhi - 1;
      const float* hr = hs + j * FD + lane;
      nb0 += hr[0]; nb1 += hr[64]; nb2 += hr[128]; nb3 += hr[192];
    }
    const float* hi = hs + i * FD + lane;
    float di = dinv[i];
    float s = fabsf(hi[0] - di * nb0) + fabsf(hi[64] - di * nb1)
            + fabsf(hi[128] - di * nb2) + fabsf(hi[192] - di * nb3);
    for (int off = 32; off; off >>= 1) s += __shfl_xor(s, off);
    if (lane == 0) sc[i] = s;
  }
  __syncthreads();
  if (tid < NN1) {
    float my = sc[tid];
    int cnt = 0;
    for (int j = 0; j < NN1; ++j) {
      float sj = sc[j];
      cnt += (sj > my) || (sj == my && j < tid);
    }
    if (cnt < NN2) sel[cnt] = tid;
  }
  __syncthreads();
  float* zb = zbuf + (size_t)bl * 8192;
  for (int r = wv; r < NN2; r += 4) {
    const float* hr = hs + sel[r] * FD + lane;
    float* dst = zb + r * FD + lane;
    dst[0] = hr[0]; dst[64] = hr[64]; dst[128] = hr[128]; dst[192] = hr[192];
  }
  {
    float mx = -3.402823466e38f, sm2 = 0.0f;
    for (int r = 0; r < NN2; ++r) {
      float v = hs[sel[r] * FD + tid];
      mx = fmaxf(mx, v); sm2 += v;
    }
    zb[7680 + tid] = mx;
    zb[7936 + tid] = sm2 / 28.0f;
  }
}

// ---------------------------------------------------------------------------
// K5: fused lin1. Block = 8 graphs x full K x all 256 cols. 512 thr.
// z read contiguous exactly once; w streamed (L2-resident, lockstep blocks).
// col = tid&63 (4 cols), ksub = tid>>6 (k-subgroup of 4 within 32-k tile).
// LDS: wt[32][260] + zt[32][8]; epilogue reduces 8 ksub partials via LDS tree.
// ---------------------------------------------------------------------------
__global__ __launch_bounds__(512) void k_lin1f(
    const float* __restrict__ zbuf, const float* __restrict__ w,
    const float* __restrict__ bias, float* __restrict__ fbuf)
{
  __shared__ float smem[8576];           // wt: 32*260=8320 | zt: 32*8=256
  float* wt = smem;
  float* zt = smem + 8320;

  const int tid = threadIdx.x;
  const int col = tid & 63;
  const int ksub = tid >> 6;             // 0..7
  const int g0 = blockIdx.x * 8;
  const int gz = tid >> 5, kz = tid & 31;  // z staging (tid<256)

  float acc[8][4];
#pragma unroll
  for (int g = 0; g < 8; ++g)
#pragma unroll
    for (int c = 0; c < 4; ++c) acc[g][c] = 0.f;

  const float* wbase = w + (size_t)ksub * 256 + col * 4;
  const float* zbase = zbuf + (size_t)(g0 + gz) * 8192 + kz;

  float4 wr4[4]; float zr1 = 0.f;
#pragma unroll
  for (int q = 0; q < 4; ++q)
    wr4[q] = *(const float4*)(wbase + (size_t)(8 * q) * 256);
  if (tid < 256) zr1 = zbase[0];
#pragma unroll
  for (int q = 0; q < 4; ++q)
    *(float4*)&wt[(ksub + 8 * q) * 260 + col * 4] = wr4[q];
  if (tid < 256) zt[kz * 8 + gz] = zr1;
  __syncthreads();

  for (int it = 0; it < 256; ++it) {
    if (it + 1 < 256) {
      const float* wn = wbase + (size_t)(it + 1) * 32 * 256;
#pragma unroll
      for (int q = 0; q < 4; ++q)
        wr4[q] = *(const float4*)(wn + (size_t)(8 * q) * 256);
      if (tid < 256) zr1 = zbase[(it + 1) * 32];
    }
#pragma unroll
    for (int kk = 0; kk < 4; ++kk) {
      int k = ksub * 4 + kk;
      float4 za = *(const float4*)&zt[k * 8];
      float4 zb = *(const float4*)&zt[k * 8 + 4];
      float4 wv = *(const float4*)&wt[k * 260 + col * 4];
      acc[0][0] += za.x * wv.x; acc[0][1] += za.x * wv.y; acc[0][2] += za.x * wv.z; acc[0][3] += za.x * wv.w;
      acc[1][0] += za.y * wv.x; acc[1][1] += za.y * wv.y; acc[1][2] += za.y * wv.z; acc[1][3] += za.y * wv.w;
      acc[2][0] += za.z * wv.x; acc[2][1] += za.z * wv.y; acc[2][2] += za.z * wv.z; acc[2][3] += za.z * wv.w;
      acc[3][0] += za.w * wv.x; acc[3][1] += za.w * wv.y; acc[3][2] += za.w * wv.z; acc[3][3] += za.w * wv.w;
      acc[4][0] += zb.x * wv.x; acc[4][1] += zb.x * wv.y; acc[4][2] += zb.x * wv.z; acc[4][3] += zb.x * wv.w;
      acc[5][0] += zb.y * wv.x; acc[5][1] += zb.y * wv.y; acc[5][2] += zb.y * wv.z; acc[5][3] += zb.y * wv.w;
      acc[6][0] += zb.z * wv.x; acc[6][1] += zb.z * wv.y; acc[6][2] += zb.z * wv.z; acc[6][3] += zb.z * wv.w;
      acc[7][0] += zb.w * wv.x; acc[7][1] += zb.w * wv.y; acc[7][2] += zb.w * wv.z; acc[7][3] += zb.w * wv.w;
    }
    __syncthreads();
    if (it + 1 < 256) {
#pragma unroll
      for (int q = 0; q < 4; ++q)
        *(float4*)&wt[(ksub + 8 * q) * 260 + col * 4] = wr4[q];
      if (tid < 256) zt[kz * 8 + gz] = zr1;
      __syncthreads();
    }
  }

  // reduce 8 ksub partials (tree via LDS, stride 33 = conflict-free)
  float* red = smem;
  for (int half = 4; half >= 1; half >>= 1) {
    if (ksub >= half && ksub < 2 * half) {
      float* dst = red + ((ksub - half) * 64 + col) * 33;
#pragma unroll
      for (int g = 0; g < 8; ++g)
#pragma unroll
        for (int c = 0; c < 4; ++c) dst[g * 4 + c] = acc[g][c];
    }
    __syncthreads();
    if (ksub < half) {
      const float* src = red + (ksub * 64 + col) * 33;
#pragma unroll
      for (int g = 0; g < 8; ++g)
#pragma unroll
        for (int c = 0; c < 4; ++c) acc[g][c] += src[g * 4 + c];
    }
    __syncthreads();
  }
  if (ksub == 0) {
    float4 bv = *(const float4*)(bias + col * 4);
#pragma unroll
    for (int g = 0; g < 8; ++g) {
      float4 o;
      o.x = fmaxf(acc[g][0] + bv.x, 0.f);
      o.y = fmaxf(acc[g][1] + bv.y, 0.f);
      o.z = fmaxf(acc[g][2] + bv.z, 0.f);
      o.w = fmaxf(acc[g][3] + bv.w, 0.f);
      *(float4*)&fbuf[(size_t)(g0 + g) * 256 + col * 4] = o;
    }
  }
}

// ---------------------------------------------------------------------------
// K6: features = relu(f @ lin2_w + b2); x_lo = softmax(features)
// ---------------------------------------------------------------------------
__global__ __launch_bounds__(128) void k_head(
    const float* __restrict__ fbuf, const float* __restrict__ w2,
    const float* __restrict__ b2, float* __restrict__ out, int b0)
{
  __shared__ __align__(16) float fs[256];
  __shared__ float red[2];
  const int tid = threadIdx.x, lane = tid & 63, wv = tid >> 6;
  const int bl = blockIdx.x, b = b0 + bl;
  for (int i = tid; i < 256; i += 128) fs[i] = fbuf[(size_t)bl * 256 + i];
  __syncthreads();
  float acc = b2[tid];
  for (int k = 0; k < 256; k += 4) {
    float4 fq = *(const float4*)(fs + k);
    acc += fq.x * w2[(k + 0) * 128 + tid] + fq.y * w2[(k + 1) * 128 + tid]
         + fq.z * w2[(k + 2) * 128 + tid] + fq.w * w2[(k + 3) * 128 + tid];
  }
  float feat = fmaxf(acc, 0.0f);
  out[(size_t)(NB * 128) + (size_t)b * 128 + tid] = feat;
  float m = feat;
  for (int off = 32; off; off >>= 1) m = fmaxf(m, __shfl_xor(m, off));
  if (lane == 0) red[wv] = m;
  __syncthreads();
  m = fmaxf(red[0], red[1]);
  float e = expf(feat - m);
  float s = e;
  for (int off = 32; off; off >>= 1) s += __shfl_xor(s, off);
  __syncthreads();
  if (lane == 0) red[wv] = s;
  __syncthreads();
  s = red[0] + red[1];
  out[(size_t)b * 128 + tid] = e / s;
}

// ---------------------------------------------------------------------------
extern "C" void kernel_launch(void* const* d_in, const int* in_sizes, int n_in,
                              void* d_out, int out_size, void* d_ws, size_t ws_size,
                              hipStream_t stream) {
  const float* x    = (const float*)d_in[0];
  const float* adj  = (const float*)d_in[1];
  const float* wg1  = (const float*)d_in[2];
  const float* wsp1 = (const float*)d_in[3];
  const float* wg2  = (const float*)d_in[4];
  const float* wsp2 = (const float*)d_in[5];
  const float* l1w  = (const float*)d_in[6];
  const float* l1b  = (const float*)d_in[7];
  const float* l2w  = (const float*)d_in[8];
  const float* l2b  = (const float*)d_in[9];
  float* out = (float*)d_out;

  auto al = [](size_t v) { return (v + 255) & ~(size_t)255; };
  size_t oh1, ohp1, oadjp, oz, of;
  auto plan = [&](int g) -> size_t {
    size_t o = 0;
    oh1 = o;   o += al((size_t)g * NN0 * FD * 4);   // h1 (h2 overlay)
    ohp1 = o;  o += al((size_t)g * NN1 * FD * 4);
    oadjp = o; o += al((size_t)g * NN1 * 8);
    oz = o;    o += al((size_t)g * 8192 * 4);
    of = o;    o += al((size_t)g * FD * 4);
    return o;
  };
  int G = 2048;
  while (G > 64 && plan(G) > ws_size) G >>= 1;
  if (plan(G) > ws_size) return;

  char* wsb = (char*)d_ws;
  float* h1  = (float*)(wsb + oh1);
  float* hp1 = (float*)(wsb + ohp1);
  unsigned long long* adjp = (unsigned long long*)(wsb + oadjp);
  float* zbuf = (float*)(wsb + oz);
  float* fbuf = (float*)(wsb + of);

  const size_t LDS1 = (size_t)(NN0*112 + 2*NN0*64 + 448 + 224) * 4;     // 109,248
  const size_t LDS2 = (size_t)(NN0*FD + 448 + 112 + 112 + 56) * 4;      // 116,576
  const size_t LDS3 = (size_t)(NN1*FD + 2*NN1*64 + 112 + 64 + 64) * 4;  // 86,976
  const size_t LDS4 = (size_t)(NN1*FD + 112 + 64 + 64 + 32) * 4;        // 58,432

  for (int b0 = 0; b0 < NB; b0 += G) {
    k_stage1<<<G, 512, LDS1, stream>>>(x, adj, wg1, wsp1, h1, b0);
    k_pool1<<<G, 512, LDS2, stream>>>(h1, adj, hp1, adjp, zbuf, b0);
    k_stage2<<<G, 512, LDS3, stream>>>(hp1, adjp, wg2, wsp2, h1);
    k_pool2<<<G, 256, LDS4, stream>>>(h1, adjp, zbuf);
    k_lin1f<<<G / 8, 512, 0, stream>>>(zbuf, l1w, l1b, fbuf);
    k_head<<<G, 128, 0, stream>>>(fbuf, l2w, l2b, out, b0);
  }
}

// Round 7
// 4785.321 us; speedup vs baseline: 1.8335x; 1.0049x over previous
//
#include <hip/hip_runtime.h>
#include <hip/hip_bf16.h>

#define NB   2048
#define NN0  111
#define NN1  56
#define NN2  28
#define FD   256
#define HD   128

// ---------------------------------------------------------------------------
// K1: stage-1 conv. One block/graph, 512 thr = (col 0..63) x (wave 0..7).
// GEMM: xs broadcast b128 reads, 4 weight matrices at once.
// Props: wave-uniform row; 4-way ILP bitmask walk with zero-row padding.
// ---------------------------------------------------------------------------
__global__ __launch_bounds__(512) void k_stage1(
    const float* __restrict__ x, const float* __restrict__ adj,
    const float* __restrict__ wg, const float* __restrict__ wsp,
    float* __restrict__ h1, int b0)
{
  extern __shared__ float sm[];
  float* xs   = sm;                                // 111*112 = 12432
  float* bufA = xs + NN0 * 112;                    // 112*64 = 7168 (row 111 = 0)
  float* bufB = bufA + 112 * 64;                   // 7168 (row 111 = 0)
  unsigned* abits = (unsigned*)(bufB + 112 * 64);  // 448 u32
  float* dis0 = (float*)(abits + 448);             // 112
  float* dis1 = dis0 + 112;                        // 112

  const int tid  = threadIdx.x;
  const int lane = tid & 63;   // col
  const int wv   = tid >> 6;   // row group
  const int b    = b0 + blockIdx.x;
  const float* xb = x   + (size_t)b * (NN0 * NN0);
  const float* ab = adj + (size_t)b * (NN0 * NN0);

  for (int idx = tid; idx < NN0 * NN0; idx += 512) {
    int i = idx / NN0, k = idx - i * NN0;
    xs[i * 112 + k] = xb[idx];
  }
  if (tid < 64) { bufA[111 * 64 + tid] = 0.0f; bufB[111 * 64 + tid] = 0.0f; }
  for (int i = wv; i < NN0; i += 8) {
    unsigned long long m0 = __ballot(ab[i * NN0 + lane] != 0.0f);
    float a1v = (64 + lane < NN0) ? ab[i * NN0 + 64 + lane] : 0.0f;
    unsigned long long m1 = __ballot(a1v != 0.0f);
    if (lane == 0) {
      abits[i * 4 + 0] = (unsigned)m0; abits[i * 4 + 1] = (unsigned)(m0 >> 32);
      abits[i * 4 + 2] = (unsigned)m1; abits[i * 4 + 3] = (unsigned)(m1 >> 32);
      int d = __popcll(m0) + __popcll(m1);
      dis0[i] = (d > 0) ? (1.0f / sqrtf((float)d)) : 0.0f;
      dis1[i] = 1.0f / sqrtf((float)(d + 1));
    }
  }
  __syncthreads();

  // 4-way ILP neighbor sum; invalid slots hit zero row 111.
  // NOTE: readfirstlane returns int -> must truncate to unsigned BEFORE
  // widening to u64 (sign-extension corrupted the mask in round 6).
  auto nsum = [&](int i, const float* buf) {
    const unsigned* rb = abits + i * 4;
    unsigned lo0 = (unsigned)__builtin_amdgcn_readfirstlane(rb[0]);
    unsigned hi0 = (unsigned)__builtin_amdgcn_readfirstlane(rb[1]);
    unsigned lo1 = (unsigned)__builtin_amdgcn_readfirstlane(rb[2]);
    unsigned hi1 = (unsigned)__builtin_amdgcn_readfirstlane(rb[3]);
    unsigned long long u0 = ((unsigned long long)hi0 << 32) | (unsigned long long)lo0;
    unsigned long long u1 = ((unsigned long long)hi1 << 32) | (unsigned long long)lo1;
    float s0 = 0.f, s1 = 0.f, s2 = 0.f, s3 = 0.f;
    while (u0 | u1) {
      int j0 = u0 ? (int)__builtin_ctzll(u0) : 111; u0 &= u0 - 1;
      int j1 = u0 ? (int)__builtin_ctzll(u0) : 111; u0 &= u0 - 1;
      int j2 = u1 ? (int)(64 + __builtin_ctzll(u1)) : 111; u1 &= u1 - 1;
      int j3 = u1 ? (int)(64 + __builtin_ctzll(u1)) : 111; u1 &= u1 - 1;
      s0 += buf[j0 * 64 + lane];
      s1 += buf[j1 * 64 + lane];
      s2 += buf[j2 * 64 + lane];
      s3 += buf[j3 * 64 + lane];
    }
    return (s0 + s1) + (s2 + s3);
  };

  float* h1b = h1 + (size_t)blockIdx.x * (NN0 * FD);

  for (int c = 0; c < 2; ++c) {
    const int c0 = c * 64;
    float aG[14], a2[14], a1[14], a0v[14];
#pragma unroll
    for (int t = 0; t < 14; ++t) { aG[t] = 0.f; a2[t] = 0.f; a1[t] = 0.f; a0v[t] = 0.f; }
    const float* pG = wg  + c0 + lane;
    const float* p2 = wsp + 2 * (NN0 * HD) + c0 + lane;
    const float* p1 = wsp + 1 * (NN0 * HD) + c0 + lane;
    const float* p0 = wsp + c0 + lane;
    for (int kq = 0; kq < 27; ++kq) {
      int k0 = kq * 4;
      float g0 = pG[(k0+0)*HD], g1 = pG[(k0+1)*HD], g2 = pG[(k0+2)*HD], g3 = pG[(k0+3)*HD];
      float s0 = p2[(k0+0)*HD], s1 = p2[(k0+1)*HD], s2 = p2[(k0+2)*HD], s3 = p2[(k0+3)*HD];
      float u0 = p1[(k0+0)*HD], u1 = p1[(k0+1)*HD], u2 = p1[(k0+2)*HD], u3 = p1[(k0+3)*HD];
      float v0 = p0[(k0+0)*HD], v1 = p0[(k0+1)*HD], v2 = p0[(k0+2)*HD], v3 = p0[(k0+3)*HD];
#pragma unroll
      for (int t = 0; t < 14; ++t) {
        int r = wv + 8 * t;
        if (r < NN0) {
          float4 xq = *(const float4*)(xs + r * 112 + k0);
          aG[t]  += xq.x*g0 + xq.y*g1 + xq.z*g2 + xq.w*g3;
          a2[t]  += xq.x*s0 + xq.y*s1 + xq.z*s2 + xq.w*s3;
          a1[t]  += xq.x*u0 + xq.y*u1 + xq.z*u2 + xq.w*u3;
          a0v[t] += xq.x*v0 + xq.y*v1 + xq.z*v2 + xq.w*v3;
        }
      }
    }
#pragma unroll
    for (int k = 108; k < 111; ++k) {
      float gv = pG[k*HD], sv = p2[k*HD], uv = p1[k*HD], vv = p0[k*HD];
#pragma unroll
      for (int t = 0; t < 14; ++t) {
        int r = wv + 8 * t;
        if (r < NN0) {
          float xv = xs[r * 112 + k];
          aG[t] += xv * gv; a2[t] += xv * sv; a1[t] += xv * uv; a0v[t] += xv * vv;
        }
      }
    }

#pragma unroll
    for (int t = 0; t < 14; ++t) {
      int r = wv + 8 * t;
      if (r < NN0) bufA[r * 64 + lane] = dis1[r] * aG[t];
    }
    __syncthreads();
    for (int t = 0; t < 14; ++t) {
      int i = wv + 8 * t;
      if (i < NN0) {
        float acc = bufA[i * 64 + lane] + nsum(i, bufA);
        h1b[i * FD + c0 + lane] = fmaxf(dis1[i] * acc, 0.0f);
      }
    }
    __syncthreads();
#pragma unroll
    for (int t = 0; t < 14; ++t) {
      int r = wv + 8 * t;
      if (r < NN0) bufA[r * 64 + lane] = dis0[r] * a2[t];
    }
    __syncthreads();
    float cacc[14];
    for (int t = 0; t < 14; ++t) {
      int i = wv + 8 * t;
      if (i < NN0) {
        float s = nsum(i, bufA);
        bufB[i * 64 + lane] = -dis0[i] * dis0[i] * s;
        cacc[t] = -a2[t];
      } else cacc[t] = 0.f;
    }
    __syncthreads();
#pragma unroll
    for (int t = 0; t < 14; ++t) {
      int r = wv + 8 * t;
      if (r < NN0) bufA[r * 64 + lane] = dis0[r] * a1[t];
    }
    for (int t = 0; t < 14; ++t) {
      int i = wv + 8 * t;
      if (i < NN0) {
        float v = nsum(i, bufB);
        cacc[t] -= 2.0f * dis0[i] * v;
      }
    }
    __syncthreads();
    for (int t = 0; t < 14; ++t) {
      int i = wv + 8 * t;
      if (i < NN0) {
        float tl = nsum(i, bufA);
        float o = cacc[t] - dis0[i] * tl + a0v[t];
        h1b[i * FD + HD + c0 + lane] = fmaxf(o, 0.0f);
      }
    }
    __syncthreads();
  }
}

// ---------------------------------------------------------------------------
// K2: pool1 — exact f32 scores, stable top-56, gather, adjp, x1 readout
// ---------------------------------------------------------------------------
__global__ __launch_bounds__(512) void k_pool1(
    const float* __restrict__ h1, const float* __restrict__ adj,
    float* __restrict__ hp1, unsigned long long* __restrict__ adjp,
    float* __restrict__ zbuf, int b0)
{
  extern __shared__ float smemf[];
  float* hs = smemf;                               // 111*256
  unsigned* abits = (unsigned*)(hs + NN0 * FD);    // 448
  float* dinv = (float*)(abits + 448);             // 112
  float* sc = dinv + 112;                          // 112
  int* sel = (int*)(sc + 112);                     // 56

  const int tid = threadIdx.x, lane = tid & 63, wv = tid >> 6;
  const int bl = blockIdx.x;
  const int b = b0 + bl;
  const float* hb = h1 + (size_t)bl * (NN0 * FD);
  const float* ab = adj + (size_t)b * (NN0 * NN0);

  for (int q = tid; q < NN0 * 64; q += 512)
    ((float4*)hs)[q] = ((const float4*)hb)[q];
  for (int i = wv; i < NN0; i += 8) {
    unsigned long long m0 = __ballot(ab[i * NN0 + lane] != 0.0f);
    float a1v = (64 + lane < NN0) ? ab[i * NN0 + 64 + lane] : 0.0f;
    unsigned long long m1 = __ballot(a1v != 0.0f);
    if (lane == 0) {
      abits[i * 4 + 0] = (unsigned)m0; abits[i * 4 + 1] = (unsigned)(m0 >> 32);
      abits[i * 4 + 2] = (unsigned)m1; abits[i * 4 + 3] = (unsigned)(m1 >> 32);
      int d = __popcll(m0) + __popcll(m1);
      dinv[i] = (d > 0) ? (1.0f / (float)d) : 0.0f;
    }
  }
  __syncthreads();
  for (int i = wv; i < NN0; i += 8) {
    float nb0 = 0, nb1 = 0, nb2 = 0, nb3 = 0;
    const unsigned* rb = abits + i * 4;
#pragma unroll
    for (int w4 = 0; w4 < 4; ++w4) {
      unsigned u = (unsigned)__builtin_amdgcn_readfirstlane(rb[w4]);
      while (u) {
        int j = (w4 << 5) + __builtin_ctz(u); u &= u - 1;
        const float* hr = hs + j * FD + lane;
        nb0 += hr[0]; nb1 += hr[64]; nb2 += hr[128]; nb3 += hr[192];
      }
    }
    const float* hi = hs + i * FD + lane;
    float di = dinv[i];
    float s = fabsf(hi[0] - di * nb0) + fabsf(hi[64] - di * nb1)
            + fabsf(hi[128] - di * nb2) + fabsf(hi[192] - di * nb3);
    for (int off = 32; off; off >>= 1) s += __shfl_xor(s, off);
    if (lane == 0) sc[i] = s;
  }
  __syncthreads();
  if (tid < NN0) {
    float my = sc[tid];
    int cnt = 0;
    for (int j = 0; j < NN0; ++j) {
      float sj = sc[j];
      cnt += (sj > my) || (sj == my && j < tid);
    }
    if (cnt < NN1) sel[cnt] = tid;
  }
  __syncthreads();
  float* hpb = hp1 + (size_t)bl * (NN1 * FD);
  for (int r = wv; r < NN1; r += 8) {
    int i = sel[r];
    const float* hr = hs + i * FD + lane;
    float* dst = hpb + r * FD + lane;
    dst[0] = hr[0]; dst[64] = hr[64]; dst[128] = hr[128]; dst[192] = hr[192];
    int j2 = (lane < NN1) ? sel[lane] : 0;
    bool bit = (lane < NN1) && ((abits[i * 4 + (j2 >> 5)] >> (j2 & 31)) & 1);
    unsigned long long m = __ballot(bit);
    if (lane == 0) adjp[(size_t)bl * NN1 + r] = m;
  }
  __syncthreads();
  float* zb = zbuf + (size_t)bl * 8192;
  if (tid < FD) {
    float mx = -3.402823466e38f, sm2 = 0.0f;
    for (int r = 0; r < NN1; ++r) {
      float v = hs[sel[r] * FD + tid];
      mx = fmaxf(mx, v); sm2 += v;
    }
    zb[7168 + tid] = mx;
    zb[7424 + tid] = sm2 / 56.0f;
  }
}

// ---------------------------------------------------------------------------
// K3: stage-2 conv (56 nodes, K=256); 4-way ILP nsum with zero row 56.
// ---------------------------------------------------------------------------
__global__ __launch_bounds__(512) void k_stage2(
    const float* __restrict__ hp1, const unsigned long long* __restrict__ adjp,
    const float* __restrict__ wg, const float* __restrict__ wsp,
    float* __restrict__ h2)
{
  extern __shared__ float sm[];
  float* hs   = sm;                                // 56*256 = 14336
  float* bufA = hs + NN1 * FD;                     // 57*64 = 3648 (row 56 = 0)
  float* bufB = bufA + 57 * 64;                    // 3648
  unsigned long long* rowm = (unsigned long long*)(bufB + 57 * 64); // 56
  float* dis0 = (float*)(rowm + 56);               // 64
  float* dis1 = dis0 + 64;                         // 64

  const int tid = threadIdx.x, lane = tid & 63, wv = tid >> 6;
  const int bl = blockIdx.x;
  const float* hb = hp1 + (size_t)bl * (NN1 * FD);
  for (int q = tid; q < NN1 * 64; q += 512)
    ((float4*)hs)[q] = ((const float4*)hb)[q];
  if (tid < 64) { bufA[56 * 64 + tid] = 0.0f; bufB[56 * 64 + tid] = 0.0f; }
  if (tid < NN1) {
    unsigned long long m = adjp[(size_t)bl * NN1 + tid];
    rowm[tid] = m;
    int d = __popcll(m);
    dis0[tid] = (d > 0) ? (1.0f / sqrtf((float)d)) : 0.0f;
    dis1[tid] = 1.0f / sqrtf((float)(d + 1));
  }
  __syncthreads();

  auto nsum = [&](int i, const float* buf) {
    unsigned long long m = rowm[i];
    unsigned lo = (unsigned)__builtin_amdgcn_readfirstlane((unsigned)m);
    unsigned hi = (unsigned)__builtin_amdgcn_readfirstlane((unsigned)(m >> 32));
    unsigned long long u = ((unsigned long long)hi << 32) | (unsigned long long)lo;
    float s0 = 0.f, s1 = 0.f, s2 = 0.f, s3 = 0.f;
    while (u) {
      int j0 = (int)__builtin_ctzll(u); u &= u - 1;
      int j1 = u ? (int)__builtin_ctzll(u) : 56; u &= u - 1;
      int j2 = u ? (int)__builtin_ctzll(u) : 56; u &= u - 1;
      int j3 = u ? (int)__builtin_ctzll(u) : 56; u &= u - 1;
      s0 += buf[j0 * 64 + lane];
      s1 += buf[j1 * 64 + lane];
      s2 += buf[j2 * 64 + lane];
      s3 += buf[j3 * 64 + lane];
    }
    return (s0 + s1) + (s2 + s3);
  };

  float* h2b = h2 + (size_t)bl * (NN1 * FD);

  for (int c = 0; c < 2; ++c) {
    const int c0 = c * 64;
    float aG[7], a2[7], a1[7], a0v[7];
#pragma unroll
    for (int t = 0; t < 7; ++t) { aG[t] = 0.f; a2[t] = 0.f; a1[t] = 0.f; a0v[t] = 0.f; }
    const float* pG = wg  + c0 + lane;
    const float* p2 = wsp + 2 * (FD * HD) + c0 + lane;
    const float* p1 = wsp + 1 * (FD * HD) + c0 + lane;
    const float* p0 = wsp + c0 + lane;
    for (int kq = 0; kq < 64; ++kq) {
      int k0 = kq * 4;
      float g0 = pG[(k0+0)*HD], g1 = pG[(k0+1)*HD], g2 = pG[(k0+2)*HD], g3 = pG[(k0+3)*HD];
      float s0 = p2[(k0+0)*HD], s1 = p2[(k0+1)*HD], s2 = p2[(k0+2)*HD], s3 = p2[(k0+3)*HD];
      float u0 = p1[(k0+0)*HD], u1 = p1[(k0+1)*HD], u2 = p1[(k0+2)*HD], u3 = p1[(k0+3)*HD];
      float v0 = p0[(k0+0)*HD], v1 = p0[(k0+1)*HD], v2 = p0[(k0+2)*HD], v3 = p0[(k0+3)*HD];
#pragma unroll
      for (int t = 0; t < 7; ++t) {
        int r = wv + 8 * t;
        float4 xq = *(const float4*)(hs + r * FD + k0);
        aG[t]  += xq.x*g0 + xq.y*g1 + xq.z*g2 + xq.w*g3;
        a2[t]  += xq.x*s0 + xq.y*s1 + xq.z*s2 + xq.w*s3;
        a1[t]  += xq.x*u0 + xq.y*u1 + xq.z*u2 + xq.w*u3;
        a0v[t] += xq.x*v0 + xq.y*v1 + xq.z*v2 + xq.w*v3;
      }
    }
#pragma unroll
    for (int t = 0; t < 7; ++t) bufA[(wv + 8*t) * 64 + lane] = dis1[wv + 8*t] * aG[t];
    __syncthreads();
#pragma unroll
    for (int t = 0; t < 7; ++t) {
      int i = wv + 8 * t;
      float acc = bufA[i * 64 + lane] + nsum(i, bufA);
      h2b[i * FD + c0 + lane] = fmaxf(dis1[i] * acc, 0.0f);
    }
    __syncthreads();
#pragma unroll
    for (int t = 0; t < 7; ++t) bufA[(wv + 8*t) * 64 + lane] = dis0[wv + 8*t] * a2[t];
    __syncthreads();
    float cacc[7];
#pragma unroll
    for (int t = 0; t < 7; ++t) {
      int i = wv + 8 * t;
      float s = nsum(i, bufA);
      bufB[i * 64 + lane] = -dis0[i] * dis0[i] * s;
      cacc[t] = -a2[t];
    }
    __syncthreads();
#pragma unroll
    for (int t = 0; t < 7; ++t) bufA[(wv + 8*t) * 64 + lane] = dis0[wv + 8*t] * a1[t];
#pragma unroll
    for (int t = 0; t < 7; ++t) {
      int i = wv + 8 * t;
      float v = nsum(i, bufB);
      cacc[t] -= 2.0f * dis0[i] * v;
    }
    __syncthreads();
#pragma unroll
    for (int t = 0; t < 7; ++t) {
      int i = wv + 8 * t;
      float tl = nsum(i, bufA);
      float o = cacc[t] - dis0[i] * tl + a0v[t];
      h2b[i * FD + HD + c0 + lane] = fmaxf(o, 0.0f);
    }
    __syncthreads();
  }
}

// ---------------------------------------------------------------------------
// K4: pool2 + readout; flat h -> zbuf[0..7167], x2 -> zbuf[7680..]
// ---------------------------------------------------------------------------
__global__ __launch_bounds__(256) void k_pool2(
    const float* __restrict__ h2, const unsigned long long* __restrict__ adjp,
    float* __restrict__ zbuf)
{
  extern __shared__ float smemf[];
  float* hs = smemf;                                        // 56*256
  unsigned long long* rowm = (unsigned long long*)(hs + NN1 * FD);
  float* dinv = (float*)(rowm + 56);
  float* sc = dinv + 64;
  int* sel = (int*)(sc + 64);

  const int tid = threadIdx.x, lane = tid & 63, wv = tid >> 6;
  const int bl = blockIdx.x;
  const float* hb = h2 + (size_t)bl * (NN1 * FD);
  for (int q = tid; q < NN1 * 64; q += 256)
    ((float4*)hs)[q] = ((const float4*)hb)[q];
  if (tid < NN1) {
    unsigned long long m = adjp[(size_t)bl * NN1 + tid];
    rowm[tid] = m;
    int d = __popcll(m);
    dinv[tid] = (d > 0) ? (1.0f / (float)d) : 0.0f;
  }
  __syncthreads();
  for (int i = wv; i < NN1; i += 4) {
    float nb0 = 0, nb1 = 0, nb2 = 0, nb3 = 0;
    unsigned long long m = rowm[i];
    unsigned ulo = (unsigned)__builtin_amdgcn_readfirstlane((unsigned)m);
    unsigned uhi = (unsigned)__builtin_amdgcn_readfirstlane((unsigned)(m >> 32));
    while (ulo) {
      int j = __builtin_ctz(ulo); ulo &= ulo - 1;
      const float* hr = hs + j * FD + lane;
      nb0 += hr[0]; nb1 += hr[64]; nb2 += hr[128]; nb3 += hr[192];
    }
    while (uhi) {
      int j = 32 + __builtin_ctz(uhi); uhi &= uhi - 1;
      const float* hr = hs + j * FD + lane;
      nb0 += hr[0]; nb1 += hr[64]; nb2 += hr[128]; nb3 += hr[192];
    }
    const float* hi = hs + i * FD + lane;
    float di = dinv[i];
    float s = fabsf(hi[0] - di * nb0) + fabsf(hi[64] - di * nb1)
            + fabsf(hi[128] - di * nb2) + fabsf(hi[192] - di * nb3);
    for (int off = 32; off; off >>= 1) s += __shfl_xor(s, off);
    if (lane == 0) sc[i] = s;
  }
  __syncthreads();
  if (tid < NN1) {
    float my = sc[tid];
    int cnt = 0;
    for (int j = 0; j < NN1; ++j) {
      float sj = sc[j];
      cnt += (sj > my) || (sj == my && j < tid);
    }
    if (cnt < NN2) sel[cnt] = tid;
  }
  __syncthreads();
  float* zb = zbuf + (size_t)bl * 8192;
  for (int r = wv; r < NN2; r += 4) {
    const float* hr = hs + sel[r] * FD + lane;
    float* dst = zb + r * FD + lane;
    dst[0] = hr[0]; dst[64] = hr[64]; dst[128] = hr[128]; dst[192] = hr[192];
  }
  {
    float mx = -3.402823466e38f, sm2 = 0.0f;
    for (int r = 0; r < NN2; ++r) {
      float v = hs[sel[r] * FD + tid];
      mx = fmaxf(mx, v); sm2 += v;
    }
    zb[7680 + tid] = mx;
    zb[7936 + tid] = sm2 / 28.0f;
  }
}

// ---------------------------------------------------------------------------
// K5: fused lin1. Block = 8 graphs x full K x all 256 cols. 512 thr.
// ---------------------------------------------------------------------------
__global__ __launch_bounds__(512) void k_lin1f(
    const float* __restrict__ zbuf, const float* __restrict__ w,
    const float* __restrict__ bias, float* __restrict__ fbuf)
{
  __shared__ float smem[8576];           // wt: 32*260=8320 | zt: 32*8=256
  float* wt = smem;
  float* zt = smem + 8320;

  const int tid = threadIdx.x;
  const int col = tid & 63;
  const int ksub = tid >> 6;             // 0..7
  const int g0 = blockIdx.x * 8;
  const int gz = tid >> 5, kz = tid & 31;  // z staging (tid<256)

  float acc[8][4];
#pragma unroll
  for (int g = 0; g < 8; ++g)
#pragma unroll
    for (int c = 0; c < 4; ++c) acc[g][c] = 0.f;

  const float* wbase = w + (size_t)ksub * 256 + col * 4;
  const float* zbase = zbuf + (size_t)(g0 + gz) * 8192 + kz;

  float4 wr4[4]; float zr1 = 0.f;
#pragma unroll
  for (int q = 0; q < 4; ++q)
    wr4[q] = *(const float4*)(wbase + (size_t)(8 * q) * 256);
  if (tid < 256) zr1 = zbase[0];
#pragma unroll
  for (int q = 0; q < 4; ++q)
    *(float4*)&wt[(ksub + 8 * q) * 260 + col * 4] = wr4[q];
  if (tid < 256) zt[kz * 8 + gz] = zr1;
  __syncthreads();

  for (int it = 0; it < 256; ++it) {
    if (it + 1 < 256) {
      const float* wn = wbase + (size_t)(it + 1) * 32 * 256;
#pragma unroll
      for (int q = 0; q < 4; ++q)
        wr4[q] = *(const float4*)(wn + (size_t)(8 * q) * 256);
      if (tid < 256) zr1 = zbase[(it + 1) * 32];
    }
#pragma unroll
    for (int kk = 0; kk < 4; ++kk) {
      int k = ksub * 4 + kk;
      float4 za = *(const float4*)&zt[k * 8];
      float4 zb = *(const float4*)&zt[k * 8 + 4];
      float4 wv = *(const float4*)&wt[k * 260 + col * 4];
      acc[0][0] += za.x * wv.x; acc[0][1] += za.x * wv.y; acc[0][2] += za.x * wv.z; acc[0][3] += za.x * wv.w;
      acc[1][0] += za.y * wv.x; acc[1][1] += za.y * wv.y; acc[1][2] += za.y * wv.z; acc[1][3] += za.y * wv.w;
      acc[2][0] += za.z * wv.x; acc[2][1] += za.z * wv.y; acc[2][2] += za.z * wv.z; acc[2][3] += za.z * wv.w;
      acc[3][0] += za.w * wv.x; acc[3][1] += za.w * wv.y; acc[3][2] += za.w * wv.z; acc[3][3] += za.w * wv.w;
      acc[4][0] += zb.x * wv.x; acc[4][1] += zb.x * wv.y; acc[4][2] += zb.x * wv.z; acc[4][3] += zb.x * wv.w;
      acc[5][0] += zb.y * wv.x; acc[5][1] += zb.y * wv.y; acc[5][2] += zb.y * wv.z; acc[5][3] += zb.y * wv.w;
      acc[6][0] += zb.z * wv.x; acc[6][1] += zb.z * wv.y; acc[6][2] += zb.z * wv.z; acc[6][3] += zb.z * wv.w;
      acc[7][0] += zb.w * wv.x; acc[7][1] += zb.w * wv.y; acc[7][2] += zb.w * wv.z; acc[7][3] += zb.w * wv.w;
    }
    __syncthreads();
    if (it + 1 < 256) {
#pragma unroll
      for (int q = 0; q < 4; ++q)
        *(float4*)&wt[(ksub + 8 * q) * 260 + col * 4] = wr4[q];
      if (tid < 256) zt[kz * 8 + gz] = zr1;
      __syncthreads();
    }
  }

  // reduce 8 ksub partials (tree via LDS)
  float* red = smem;
  for (int half = 4; half >= 1; half >>= 1) {
    if (ksub >= half && ksub < 2 * half) {
      float* dst = red + ((ksub - half) * 64 + col) * 33;
#pragma unroll
      for (int g = 0; g < 8; ++g)
#pragma unroll
        for (int c = 0; c < 4; ++c) dst[g * 4 + c] = acc[g][c];
    }
    __syncthreads();
    if (ksub < half) {
      const float* src = red + (ksub * 64 + col) * 33;
#pragma unroll
      for (int g = 0; g < 8; ++g)
#pragma unroll
        for (int c = 0; c < 4; ++c) acc[g][c] += src[g * 4 + c];
    }
    __syncthreads();
  }
  if (ksub == 0) {
    float4 bv = *(const float4*)(bias + col * 4);
#pragma unroll
    for (int g = 0; g < 8; ++g) {
      float4 o;
      o.x = fmaxf(acc[g][0] + bv.x, 0.f);
      o.y = fmaxf(acc[g][1] + bv.y, 0.f);
      o.z = fmaxf(acc[g][2] + bv.z, 0.f);
      o.w = fmaxf(acc[g][3] + bv.w, 0.f);
      *(float4*)&fbuf[(size_t)(g0 + g) * 256 + col * 4] = o;
    }
  }
}

// ---------------------------------------------------------------------------
// K6: features = relu(f @ lin2_w + b2); x_lo = softmax(features)
// ---------------------------------------------------------------------------
__global__ __launch_bounds__(128) void k_head(
    const float* __restrict__ fbuf, const float* __restrict__ w2,
    const float* __restrict__ b2, float* __restrict__ out, int b0)
{
  __shared__ __align__(16) float fs[256];
  __shared__ float red[2];
  const int tid = threadIdx.x, lane = tid & 63, wv = tid >> 6;
  const int bl = blockIdx.x, b = b0 + bl;
  for (int i = tid; i < 256; i += 128) fs[i] = fbuf[(size_t)bl * 256 + i];
  __syncthreads();
  float acc = b2[tid];
  for (int k = 0; k < 256; k += 4) {
    float4 fq = *(const float4*)(fs + k);
    acc += fq.x * w2[(k + 0) * 128 + tid] + fq.y * w2[(k + 1) * 128 + tid]
         + fq.z * w2[(k + 2) * 128 + tid] + fq.w * w2[(k + 3) * 128 + tid];
  }
  float feat = fmaxf(acc, 0.0f);
  out[(size_t)(NB * 128) + (size_t)b * 128 + tid] = feat;
  float m = feat;
  for (int off = 32; off; off >>= 1) m = fmaxf(m, __shfl_xor(m, off));
  if (lane == 0) red[wv] = m;
  __syncthreads();
  m = fmaxf(red[0], red[1]);
  float e = expf(feat - m);
  float s = e;
  for (int off = 32; off; off >>= 1) s += __shfl_xor(s, off);
  __syncthreads();
  if (lane == 0) red[wv] = s;
  __syncthreads();
  s = red[0] + red[1];
  out[(size_t)b * 128 + tid] = e / s;
}

// ---------------------------------------------------------------------------
extern "C" void kernel_launch(void* const* d_in, const int* in_sizes, int n_in,
                              void* d_out, int out_size, void* d_ws, size_t ws_size,
                              hipStream_t stream) {
  const float* x    = (const float*)d_in[0];
  const float* adj  = (const float*)d_in[1];
  const float* wg1  = (const float*)d_in[2];
  const float* wsp1 = (const float*)d_in[3];
  const float* wg2  = (const float*)d_in[4];
  const float* wsp2 = (const float*)d_in[5];
  const float* l1w  = (const float*)d_in[6];
  const float* l1b  = (const float*)d_in[7];
  const float* l2w  = (const float*)d_in[8];
  const float* l2b  = (const float*)d_in[9];
  float* out = (float*)d_out;

  auto al = [](size_t v) { return (v + 255) & ~(size_t)255; };
  size_t oh1, ohp1, oadjp, oz, of;
  auto plan = [&](int g) -> size_t {
    size_t o = 0;
    oh1 = o;   o += al((size_t)g * NN0 * FD * 4);   // h1 (h2 overlay)
    ohp1 = o;  o += al((size_t)g * NN1 * FD * 4);
    oadjp = o; o += al((size_t)g * NN1 * 8);
    oz = o;    o += al((size_t)g * 8192 * 4);
    of = o;    o += al((size_t)g * FD * 4);
    return o;
  };
  int G = 2048;
  while (G > 64 && plan(G) > ws_size) G >>= 1;
  if (plan(G) > ws_size) return;

  char* wsb = (char*)d_ws;
  float* h1  = (float*)(wsb + oh1);
  float* hp1 = (float*)(wsb + ohp1);
  unsigned long long* adjp = (unsigned long long*)(wsb + oadjp);
  float* zbuf = (float*)(wsb + oz);
  float* fbuf = (float*)(wsb + of);

  const size_t LDS1 = (size_t)(NN0*112 + 2*112*64 + 448 + 224) * 4;     // 109,760
  const size_t LDS2 = (size_t)(NN0*FD + 448 + 112 + 112 + 56) * 4;      // 116,576
  const size_t LDS3 = (size_t)(NN1*FD + 2*57*64 + 112 + 64 + 64) * 4;   // 87,488
  const size_t LDS4 = (size_t)(NN1*FD + 112 + 64 + 64 + 32) * 4;        // 58,432

  for (int b0 = 0; b0 < NB; b0 += G) {
    k_stage1<<<G, 512, LDS1, stream>>>(x, adj, wg1, wsp1, h1, b0);
    k_pool1<<<G, 512, LDS2, stream>>>(h1, adj, hp1, adjp, zbuf, b0);
    k_stage2<<<G, 512, LDS3, stream>>>(hp1, adjp, wg2, wsp2, h1);
    k_pool2<<<G, 256, LDS4, stream>>>(h1, adjp, zbuf);
    k_lin1f<<<G / 8, 512, 0, stream>>>(zbuf, l1w, l1b, fbuf);
    k_head<<<G, 128, 0, stream>>>(fbuf, l2w, l2b, out, b0);
  }
}

// Round 8
// 4584.355 us; speedup vs baseline: 1.9138x; 1.0438x over previous
//
#include <hip/hip_runtime.h>
#include <hip/hip_bf16.h>

#define NB   2048
#define NN0  111
#define NN1  56
#define NN2  28
#define FD   256
#define HD   128

// ---------------------------------------------------------------------------
// K1: stage-1 conv. One block/graph, 512 thr = (col 0..63) x (wave 0..7).
// Single prop buffer (Cheb U kept in regs) -> LDS 81,088 B -> 2 blocks/CU.
// ---------------------------------------------------------------------------
__global__ __launch_bounds__(512) void k_stage1(
    const float* __restrict__ x, const float* __restrict__ adj,
    const float* __restrict__ wg, const float* __restrict__ wsp,
    float* __restrict__ h1, int b0)
{
  extern __shared__ float sm[];
  float* xs   = sm;                                // 111*112 = 12432
  float* buf  = xs + 12432;                        // 112*64 = 7168 (row 111 = 0)
  unsigned* abits = (unsigned*)(buf + 7168);       // 448 u32
  float* dis0 = (float*)(abits + 448);             // 112
  float* dis1 = dis0 + 112;                        // 112

  const int tid  = threadIdx.x;
  const int lane = tid & 63;   // col
  const int wv   = tid >> 6;   // row group
  const int b    = b0 + blockIdx.x;
  const float* xb = x   + (size_t)b * (NN0 * NN0);
  const float* ab = adj + (size_t)b * (NN0 * NN0);

  for (int idx = tid; idx < NN0 * NN0; idx += 512) {
    int i = idx / NN0, k = idx - i * NN0;
    xs[i * 112 + k] = xb[idx];
  }
  if (tid < 64) buf[111 * 64 + tid] = 0.0f;
  for (int i = wv; i < NN0; i += 8) {
    unsigned long long m0 = __ballot(ab[i * NN0 + lane] != 0.0f);
    float a1v = (64 + lane < NN0) ? ab[i * NN0 + 64 + lane] : 0.0f;
    unsigned long long m1 = __ballot(a1v != 0.0f);
    if (lane == 0) {
      abits[i * 4 + 0] = (unsigned)m0; abits[i * 4 + 1] = (unsigned)(m0 >> 32);
      abits[i * 4 + 2] = (unsigned)m1; abits[i * 4 + 3] = (unsigned)(m1 >> 32);
      int d = __popcll(m0) + __popcll(m1);
      dis0[i] = (d > 0) ? (1.0f / sqrtf((float)d)) : 0.0f;
      dis1[i] = 1.0f / sqrtf((float)(d + 1));
    }
  }
  __syncthreads();

  // 4-way ILP neighbor sum; invalid slots hit zero row 111.
  // readfirstlane returns int -> truncate to unsigned BEFORE widening.
  auto nsum = [&](int i) {
    const unsigned* rb = abits + i * 4;
    unsigned lo0 = (unsigned)__builtin_amdgcn_readfirstlane(rb[0]);
    unsigned hi0 = (unsigned)__builtin_amdgcn_readfirstlane(rb[1]);
    unsigned lo1 = (unsigned)__builtin_amdgcn_readfirstlane(rb[2]);
    unsigned hi1 = (unsigned)__builtin_amdgcn_readfirstlane(rb[3]);
    unsigned long long u0 = ((unsigned long long)hi0 << 32) | (unsigned long long)lo0;
    unsigned long long u1 = ((unsigned long long)hi1 << 32) | (unsigned long long)lo1;
    float s0 = 0.f, s1 = 0.f, s2 = 0.f, s3 = 0.f;
    while (u0 | u1) {
      int j0 = u0 ? (int)__builtin_ctzll(u0) : 111; u0 &= u0 - 1;
      int j1 = u0 ? (int)__builtin_ctzll(u0) : 111; u0 &= u0 - 1;
      int j2 = u1 ? (int)(64 + __builtin_ctzll(u1)) : 111; u1 &= u1 - 1;
      int j3 = u1 ? (int)(64 + __builtin_ctzll(u1)) : 111; u1 &= u1 - 1;
      s0 += buf[j0 * 64 + lane];
      s1 += buf[j1 * 64 + lane];
      s2 += buf[j2 * 64 + lane];
      s3 += buf[j3 * 64 + lane];
    }
    return (s0 + s1) + (s2 + s3);
  };

  float* h1b = h1 + (size_t)blockIdx.x * (NN0 * FD);

  for (int c = 0; c < 2; ++c) {
    const int c0 = c * 64;
    float aG[14], a2[14], a1[14], a0v[14];
#pragma unroll
    for (int t = 0; t < 14; ++t) { aG[t] = 0.f; a2[t] = 0.f; a1[t] = 0.f; a0v[t] = 0.f; }
    const float* pG = wg  + c0 + lane;
    const float* p2 = wsp + 2 * (NN0 * HD) + c0 + lane;
    const float* p1 = wsp + 1 * (NN0 * HD) + c0 + lane;
    const float* p0 = wsp + c0 + lane;
    for (int kq = 0; kq < 27; ++kq) {
      int k0 = kq * 4;
      float g0 = pG[(k0+0)*HD], g1 = pG[(k0+1)*HD], g2 = pG[(k0+2)*HD], g3 = pG[(k0+3)*HD];
      float s0 = p2[(k0+0)*HD], s1 = p2[(k0+1)*HD], s2 = p2[(k0+2)*HD], s3 = p2[(k0+3)*HD];
      float u0 = p1[(k0+0)*HD], u1 = p1[(k0+1)*HD], u2 = p1[(k0+2)*HD], u3 = p1[(k0+3)*HD];
      float v0 = p0[(k0+0)*HD], v1 = p0[(k0+1)*HD], v2 = p0[(k0+2)*HD], v3 = p0[(k0+3)*HD];
#pragma unroll
      for (int t = 0; t < 14; ++t) {
        int r = wv + 8 * t;
        if (r < NN0) {
          float4 xq = *(const float4*)(xs + r * 112 + k0);
          aG[t]  += xq.x*g0 + xq.y*g1 + xq.z*g2 + xq.w*g3;
          a2[t]  += xq.x*s0 + xq.y*s1 + xq.z*s2 + xq.w*s3;
          a1[t]  += xq.x*u0 + xq.y*u1 + xq.z*u2 + xq.w*u3;
          a0v[t] += xq.x*v0 + xq.y*v1 + xq.z*v2 + xq.w*v3;
        }
      }
    }
#pragma unroll
    for (int k = 108; k < 111; ++k) {
      float gv = pG[k*HD], sv = p2[k*HD], uv = p1[k*HD], vv = p0[k*HD];
#pragma unroll
      for (int t = 0; t < 14; ++t) {
        int r = wv + 8 * t;
        if (r < NN0) {
          float xv = xs[r * 112 + k];
          aG[t] += xv * gv; a2[t] += xv * sv; a1[t] += xv * uv; a0v[t] += xv * vv;
        }
      }
    }

    // ---- GCN ----
#pragma unroll
    for (int t = 0; t < 14; ++t) {
      int r = wv + 8 * t;
      if (r < NN0) buf[r * 64 + lane] = dis1[r] * aG[t];
    }
    __syncthreads();
    for (int t = 0; t < 14; ++t) {
      int i = wv + 8 * t;
      if (i < NN0) {
        float acc = buf[i * 64 + lane] + nsum(i);
        h1b[i * FD + c0 + lane] = fmaxf(dis1[i] * acc, 0.0f);
      }
    }
    __syncthreads();
    // ---- Cheb: buf = d0*P2 ----
#pragma unroll
    for (int t = 0; t < 14; ++t) {
      int r = wv + 8 * t;
      if (r < NN0) buf[r * 64 + lane] = dis0[r] * a2[t];
    }
    __syncthreads();
    float ur[14], cacc[14];
    for (int t = 0; t < 14; ++t) {
      int i = wv + 8 * t;
      if (i < NN0) {
        ur[t] = -dis0[i] * dis0[i] * nsum(i);   // U row (scaled)
        cacc[t] = -a2[t];
      } else { ur[t] = 0.f; cacc[t] = 0.f; }
    }
    __syncthreads();           // all reads of P2 done
    // ---- buf = U ----
#pragma unroll
    for (int t = 0; t < 14; ++t) {
      int r = wv + 8 * t;
      if (r < NN0) buf[r * 64 + lane] = ur[t];
    }
    __syncthreads();
    for (int t = 0; t < 14; ++t) {
      int i = wv + 8 * t;
      if (i < NN0) cacc[t] -= 2.0f * dis0[i] * nsum(i);
    }
    __syncthreads();           // all reads of U done
    // ---- buf = d0*P1 ----
#pragma unroll
    for (int t = 0; t < 14; ++t) {
      int r = wv + 8 * t;
      if (r < NN0) buf[r * 64 + lane] = dis0[r] * a1[t];
    }
    __syncthreads();
    for (int t = 0; t < 14; ++t) {
      int i = wv + 8 * t;
      if (i < NN0) {
        float o = cacc[t] - dis0[i] * nsum(i) + a0v[t];
        h1b[i * FD + HD + c0 + lane] = fmaxf(o, 0.0f);
      }
    }
    __syncthreads();           // before next half overwrites buf
  }
}

// ---------------------------------------------------------------------------
// K2: pool1 — exact f32 scores, stable top-56, gather, adjp, x1 readout
// ---------------------------------------------------------------------------
__global__ __launch_bounds__(512) void k_pool1(
    const float* __restrict__ h1, const float* __restrict__ adj,
    float* __restrict__ hp1, unsigned long long* __restrict__ adjp,
    float* __restrict__ zbuf, int b0)
{
  extern __shared__ float smemf[];
  float* hs = smemf;                               // 111*256
  unsigned* abits = (unsigned*)(hs + NN0 * FD);    // 448
  float* dinv = (float*)(abits + 448);             // 112
  float* sc = dinv + 112;                          // 112
  int* sel = (int*)(sc + 112);                     // 56

  const int tid = threadIdx.x, lane = tid & 63, wv = tid >> 6;
  const int bl = blockIdx.x;
  const int b = b0 + bl;
  const float* hb = h1 + (size_t)bl * (NN0 * FD);
  const float* ab = adj + (size_t)b * (NN0 * NN0);

  for (int q = tid; q < NN0 * 64; q += 512)
    ((float4*)hs)[q] = ((const float4*)hb)[q];
  for (int i = wv; i < NN0; i += 8) {
    unsigned long long m0 = __ballot(ab[i * NN0 + lane] != 0.0f);
    float a1v = (64 + lane < NN0) ? ab[i * NN0 + 64 + lane] : 0.0f;
    unsigned long long m1 = __ballot(a1v != 0.0f);
    if (lane == 0) {
      abits[i * 4 + 0] = (unsigned)m0; abits[i * 4 + 1] = (unsigned)(m0 >> 32);
      abits[i * 4 + 2] = (unsigned)m1; abits[i * 4 + 3] = (unsigned)(m1 >> 32);
      int d = __popcll(m0) + __popcll(m1);
      dinv[i] = (d > 0) ? (1.0f / (float)d) : 0.0f;
    }
  }
  __syncthreads();
  for (int i = wv; i < NN0; i += 8) {
    float nb0 = 0, nb1 = 0, nb2 = 0, nb3 = 0;
    const unsigned* rb = abits + i * 4;
#pragma unroll
    for (int w4 = 0; w4 < 4; ++w4) {
      unsigned u = (unsigned)__builtin_amdgcn_readfirstlane(rb[w4]);
      while (u) {
        int j = (w4 << 5) + __builtin_ctz(u); u &= u - 1;
        const float* hr = hs + j * FD + lane;
        nb0 += hr[0]; nb1 += hr[64]; nb2 += hr[128]; nb3 += hr[192];
      }
    }
    const float* hi = hs + i * FD + lane;
    float di = dinv[i];
    float s = fabsf(hi[0] - di * nb0) + fabsf(hi[64] - di * nb1)
            + fabsf(hi[128] - di * nb2) + fabsf(hi[192] - di * nb3);
    for (int off = 32; off; off >>= 1) s += __shfl_xor(s, off);
    if (lane == 0) sc[i] = s;
  }
  __syncthreads();
  if (tid < NN0) {
    float my = sc[tid];
    int cnt = 0;
    for (int j = 0; j < NN0; ++j) {
      float sj = sc[j];
      cnt += (sj > my) || (sj == my && j < tid);
    }
    if (cnt < NN1) sel[cnt] = tid;
  }
  __syncthreads();
  float* hpb = hp1 + (size_t)bl * (NN1 * FD);
  for (int r = wv; r < NN1; r += 8) {
    int i = sel[r];
    const float* hr = hs + i * FD + lane;
    float* dst = hpb + r * FD + lane;
    dst[0] = hr[0]; dst[64] = hr[64]; dst[128] = hr[128]; dst[192] = hr[192];
    int j2 = (lane < NN1) ? sel[lane] : 0;
    bool bit = (lane < NN1) && ((abits[i * 4 + (j2 >> 5)] >> (j2 & 31)) & 1);
    unsigned long long m = __ballot(bit);
    if (lane == 0) adjp[(size_t)bl * NN1 + r] = m;
  }
  __syncthreads();
  float* zb = zbuf + (size_t)bl * 8192;
  if (tid < FD) {
    float mx = -3.402823466e38f, sm2 = 0.0f;
    for (int r = 0; r < NN1; ++r) {
      float v = hs[sel[r] * FD + tid];
      mx = fmaxf(mx, v); sm2 += v;
    }
    zb[7168 + tid] = mx;
    zb[7424 + tid] = sm2 / 56.0f;
  }
}

// ---------------------------------------------------------------------------
// K3: stage-2 conv (56 nodes, K=256); single prop buffer -> LDS 72,896 B.
// ---------------------------------------------------------------------------
__global__ __launch_bounds__(512) void k_stage2(
    const float* __restrict__ hp1, const unsigned long long* __restrict__ adjp,
    const float* __restrict__ wg, const float* __restrict__ wsp,
    float* __restrict__ h2)
{
  extern __shared__ float sm[];
  float* hs   = sm;                                // 56*256 = 14336
  float* buf  = hs + NN1 * FD;                     // 57*64 = 3648 (row 56 = 0)
  unsigned long long* rowm = (unsigned long long*)(buf + 57 * 64); // 56 u64
  float* dis0 = (float*)(rowm + 56);               // 64
  float* dis1 = dis0 + 64;                         // 64

  const int tid = threadIdx.x, lane = tid & 63, wv = tid >> 6;
  const int bl = blockIdx.x;
  const float* hb = hp1 + (size_t)bl * (NN1 * FD);
  for (int q = tid; q < NN1 * 64; q += 512)
    ((float4*)hs)[q] = ((const float4*)hb)[q];
  if (tid < 64) buf[56 * 64 + tid] = 0.0f;
  if (tid < NN1) {
    unsigned long long m = adjp[(size_t)bl * NN1 + tid];
    rowm[tid] = m;
    int d = __popcll(m);
    dis0[tid] = (d > 0) ? (1.0f / sqrtf((float)d)) : 0.0f;
    dis1[tid] = 1.0f / sqrtf((float)(d + 1));
  }
  __syncthreads();

  auto nsum = [&](int i) {
    unsigned long long m = rowm[i];
    unsigned lo = (unsigned)__builtin_amdgcn_readfirstlane((unsigned)m);
    unsigned hi = (unsigned)__builtin_amdgcn_readfirstlane((unsigned)(m >> 32));
    unsigned long long u = ((unsigned long long)hi << 32) | (unsigned long long)lo;
    float s0 = 0.f, s1 = 0.f, s2 = 0.f, s3 = 0.f;
    while (u) {
      int j0 = (int)__builtin_ctzll(u); u &= u - 1;
      int j1 = u ? (int)__builtin_ctzll(u) : 56; u &= u - 1;
      int j2 = u ? (int)__builtin_ctzll(u) : 56; u &= u - 1;
      int j3 = u ? (int)__builtin_ctzll(u) : 56; u &= u - 1;
      s0 += buf[j0 * 64 + lane];
      s1 += buf[j1 * 64 + lane];
      s2 += buf[j2 * 64 + lane];
      s3 += buf[j3 * 64 + lane];
    }
    return (s0 + s1) + (s2 + s3);
  };

  float* h2b = h2 + (size_t)bl * (NN1 * FD);

  for (int c = 0; c < 2; ++c) {
    const int c0 = c * 64;
    float aG[7], a2[7], a1[7], a0v[7];
#pragma unroll
    for (int t = 0; t < 7; ++t) { aG[t] = 0.f; a2[t] = 0.f; a1[t] = 0.f; a0v[t] = 0.f; }
    const float* pG = wg  + c0 + lane;
    const float* p2 = wsp + 2 * (FD * HD) + c0 + lane;
    const float* p1 = wsp + 1 * (FD * HD) + c0 + lane;
    const float* p0 = wsp + c0 + lane;
    for (int kq = 0; kq < 64; ++kq) {
      int k0 = kq * 4;
      float g0 = pG[(k0+0)*HD], g1 = pG[(k0+1)*HD], g2 = pG[(k0+2)*HD], g3 = pG[(k0+3)*HD];
      float s0 = p2[(k0+0)*HD], s1 = p2[(k0+1)*HD], s2 = p2[(k0+2)*HD], s3 = p2[(k0+3)*HD];
      float u0 = p1[(k0+0)*HD], u1 = p1[(k0+1)*HD], u2 = p1[(k0+2)*HD], u3 = p1[(k0+3)*HD];
      float v0 = p0[(k0+0)*HD], v1 = p0[(k0+1)*HD], v2 = p0[(k0+2)*HD], v3 = p0[(k0+3)*HD];
#pragma unroll
      for (int t = 0; t < 7; ++t) {
        int r = wv + 8 * t;
        float4 xq = *(const float4*)(hs + r * FD + k0);
        aG[t]  += xq.x*g0 + xq.y*g1 + xq.z*g2 + xq.w*g3;
        a2[t]  += xq.x*s0 + xq.y*s1 + xq.z*s2 + xq.w*s3;
        a1[t]  += xq.x*u0 + xq.y*u1 + xq.z*u2 + xq.w*u3;
        a0v[t] += xq.x*v0 + xq.y*v1 + xq.z*v2 + xq.w*v3;
      }
    }
    // GCN
#pragma unroll
    for (int t = 0; t < 7; ++t) buf[(wv + 8*t) * 64 + lane] = dis1[wv + 8*t] * aG[t];
    __syncthreads();
#pragma unroll
    for (int t = 0; t < 7; ++t) {
      int i = wv + 8 * t;
      float acc = buf[i * 64 + lane] + nsum(i);
      h2b[i * FD + c0 + lane] = fmaxf(dis1[i] * acc, 0.0f);
    }
    __syncthreads();
    // Cheb: buf = d0*P2
#pragma unroll
    for (int t = 0; t < 7; ++t) buf[(wv + 8*t) * 64 + lane] = dis0[wv + 8*t] * a2[t];
    __syncthreads();
    float ur[7], cacc[7];
#pragma unroll
    for (int t = 0; t < 7; ++t) {
      int i = wv + 8 * t;
      ur[t] = -dis0[i] * dis0[i] * nsum(i);
      cacc[t] = -a2[t];
    }
    __syncthreads();
#pragma unroll
    for (int t = 0; t < 7; ++t) buf[(wv + 8*t) * 64 + lane] = ur[t];
    __syncthreads();
#pragma unroll
    for (int t = 0; t < 7; ++t) {
      int i = wv + 8 * t;
      cacc[t] -= 2.0f * dis0[i] * nsum(i);
    }
    __syncthreads();
#pragma unroll
    for (int t = 0; t < 7; ++t) buf[(wv + 8*t) * 64 + lane] = dis0[wv + 8*t] * a1[t];
    __syncthreads();
#pragma unroll
    for (int t = 0; t < 7; ++t) {
      int i = wv + 8 * t;
      float o = cacc[t] - dis0[i] * nsum(i) + a0v[t];
      h2b[i * FD + HD + c0 + lane] = fmaxf(o, 0.0f);
    }
    __syncthreads();
  }
}

// ---------------------------------------------------------------------------
// K4: pool2 + readout; flat h -> zbuf[0..7167], x2 -> zbuf[7680..]
// ---------------------------------------------------------------------------
__global__ __launch_bounds__(256) void k_pool2(
    const float* __restrict__ h2, const unsigned long long* __restrict__ adjp,
    float* __restrict__ zbuf)
{
  extern __shared__ float smemf[];
  float* hs = smemf;                                        // 56*256
  unsigned long long* rowm = (unsigned long long*)(hs + NN1 * FD);
  float* dinv = (float*)(rowm + 56);
  float* sc = dinv + 64;
  int* sel = (int*)(sc + 64);

  const int tid = threadIdx.x, lane = tid & 63, wv = tid >> 6;
  const int bl = blockIdx.x;
  const float* hb = h2 + (size_t)bl * (NN1 * FD);
  for (int q = tid; q < NN1 * 64; q += 256)
    ((float4*)hs)[q] = ((const float4*)hb)[q];
  if (tid < NN1) {
    unsigned long long m = adjp[(size_t)bl * NN1 + tid];
    rowm[tid] = m;
    int d = __popcll(m);
    dinv[tid] = (d > 0) ? (1.0f / (float)d) : 0.0f;
  }
  __syncthreads();
  for (int i = wv; i < NN1; i += 4) {
    float nb0 = 0, nb1 = 0, nb2 = 0, nb3 = 0;
    unsigned long long m = rowm[i];
    unsigned ulo = (unsigned)__builtin_amdgcn_readfirstlane((unsigned)m);
    unsigned uhi = (unsigned)__builtin_amdgcn_readfirstlane((unsigned)(m >> 32));
    while (ulo) {
      int j = __builtin_ctz(ulo); ulo &= ulo - 1;
      const float* hr = hs + j * FD + lane;
      nb0 += hr[0]; nb1 += hr[64]; nb2 += hr[128]; nb3 += hr[192];
    }
    while (uhi) {
      int j = 32 + __builtin_ctz(uhi); uhi &= uhi - 1;
      const float* hr = hs + j * FD + lane;
      nb0 += hr[0]; nb1 += hr[64]; nb2 += hr[128]; nb3 += hr[192];
    }
    const float* hi = hs + i * FD + lane;
    float di = dinv[i];
    float s = fabsf(hi[0] - di * nb0) + fabsf(hi[64] - di * nb1)
            + fabsf(hi[128] - di * nb2) + fabsf(hi[192] - di * nb3);
    for (int off = 32; off; off >>= 1) s += __shfl_xor(s, off);
    if (lane == 0) sc[i] = s;
  }
  __syncthreads();
  if (tid < NN1) {
    float my = sc[tid];
    int cnt = 0;
    for (int j = 0; j < NN1; ++j) {
      float sj = sc[j];
      cnt += (sj > my) || (sj == my && j < tid);
    }
    if (cnt < NN2) sel[cnt] = tid;
  }
  __syncthreads();
  float* zb = zbuf + (size_t)bl * 8192;
  for (int r = wv; r < NN2; r += 4) {
    const float* hr = hs + sel[r] * FD + lane;
    float* dst = zb + r * FD + lane;
    dst[0] = hr[0]; dst[64] = hr[64]; dst[128] = hr[128]; dst[192] = hr[192];
  }
  {
    float mx = -3.402823466e38f, sm2 = 0.0f;
    for (int r = 0; r < NN2; ++r) {
      float v = hs[sel[r] * FD + tid];
      mx = fmaxf(mx, v); sm2 += v;
    }
    zb[7680 + tid] = mx;
    zb[7936 + tid] = sm2 / 28.0f;
  }
}

// ---------------------------------------------------------------------------
// K5: fused lin1. Block = 8 graphs x full K x all 256 cols. 512 thr.
// ---------------------------------------------------------------------------
__global__ __launch_bounds__(512) void k_lin1f(
    const float* __restrict__ zbuf, const float* __restrict__ w,
    const float* __restrict__ bias, float* __restrict__ fbuf)
{
  __shared__ float smem[8576];           // wt: 32*260=8320 | zt: 32*8=256
  float* wt = smem;
  float* zt = smem + 8320;

  const int tid = threadIdx.x;
  const int col = tid & 63;
  const int ksub = tid >> 6;             // 0..7
  const int g0 = blockIdx.x * 8;
  const int gz = tid >> 5, kz = tid & 31;  // z staging (tid<256)

  float acc[8][4];
#pragma unroll
  for (int g = 0; g < 8; ++g)
#pragma unroll
    for (int c = 0; c < 4; ++c) acc[g][c] = 0.f;

  const float* wbase = w + (size_t)ksub * 256 + col * 4;
  const float* zbase = zbuf + (size_t)(g0 + gz) * 8192 + kz;

  float4 wr4[4]; float zr1 = 0.f;
#pragma unroll
  for (int q = 0; q < 4; ++q)
    wr4[q] = *(const float4*)(wbase + (size_t)(8 * q) * 256);
  if (tid < 256) zr1 = zbase[0];
#pragma unroll
  for (int q = 0; q < 4; ++q)
    *(float4*)&wt[(ksub + 8 * q) * 260 + col * 4] = wr4[q];
  if (tid < 256) zt[kz * 8 + gz] = zr1;
  __syncthreads();

  for (int it = 0; it < 256; ++it) {
    if (it + 1 < 256) {
      const float* wn = wbase + (size_t)(it + 1) * 32 * 256;
#pragma unroll
      for (int q = 0; q < 4; ++q)
        wr4[q] = *(const float4*)(wn + (size_t)(8 * q) * 256);
      if (tid < 256) zr1 = zbase[(it + 1) * 32];
    }
#pragma unroll
    for (int kk = 0; kk < 4; ++kk) {
      int k = ksub * 4 + kk;
      float4 za = *(const float4*)&zt[k * 8];
      float4 zb = *(const float4*)&zt[k * 8 + 4];
      float4 wv = *(const float4*)&wt[k * 260 + col * 4];
      acc[0][0] += za.x * wv.x; acc[0][1] += za.x * wv.y; acc[0][2] += za.x * wv.z; acc[0][3] += za.x * wv.w;
      acc[1][0] += za.y * wv.x; acc[1][1] += za.y * wv.y; acc[1][2] += za.y * wv.z; acc[1][3] += za.y * wv.w;
      acc[2][0] += za.z * wv.x; acc[2][1] += za.z * wv.y; acc[2][2] += za.z * wv.z; acc[2][3] += za.z * wv.w;
      acc[3][0] += za.w * wv.x; acc[3][1] += za.w * wv.y; acc[3][2] += za.w * wv.z; acc[3][3] += za.w * wv.w;
      acc[4][0] += zb.x * wv.x; acc[4][1] += zb.x * wv.y; acc[4][2] += zb.x * wv.z; acc[4][3] += zb.x * wv.w;
      acc[5][0] += zb.y * wv.x; acc[5][1] += zb.y * wv.y; acc[5][2] += zb.y * wv.z; acc[5][3] += zb.y * wv.w;
      acc[6][0] += zb.z * wv.x; acc[6][1] += zb.z * wv.y; acc[6][2] += zb.z * wv.z; acc[6][3] += zb.z * wv.w;
      acc[7][0] += zb.w * wv.x; acc[7][1] += zb.w * wv.y; acc[7][2] += zb.w * wv.z; acc[7][3] += zb.w * wv.w;
    }
    __syncthreads();
    if (it + 1 < 256) {
#pragma unroll
      for (int q = 0; q < 4; ++q)
        *(float4*)&wt[(ksub + 8 * q) * 260 + col * 4] = wr4[q];
      if (tid < 256) zt[kz * 8 + gz] = zr1;
      __syncthreads();
    }
  }

  // reduce 8 ksub partials (tree via LDS)
  float* red = smem;
  for (int half = 4; half >= 1; half >>= 1) {
    if (ksub >= half && ksub < 2 * half) {
      float* dst = red + ((ksub - half) * 64 + col) * 33;
#pragma unroll
      for (int g = 0; g < 8; ++g)
#pragma unroll
        for (int c = 0; c < 4; ++c) dst[g * 4 + c] = acc[g][c];
    }
    __syncthreads();
    if (ksub < half) {
      const float* src = red + (ksub * 64 + col) * 33;
#pragma unroll
      for (int g = 0; g < 8; ++g)
#pragma unroll
        for (int c = 0; c < 4; ++c) acc[g][c] += src[g * 4 + c];
    }
    __syncthreads();
  }
  if (ksub == 0) {
    float4 bv = *(const float4*)(bias + col * 4);
#pragma unroll
    for (int g = 0; g < 8; ++g) {
      float4 o;
      o.x = fmaxf(acc[g][0] + bv.x, 0.f);
      o.y = fmaxf(acc[g][1] + bv.y, 0.f);
      o.z = fmaxf(acc[g][2] + bv.z, 0.f);
      o.w = fmaxf(acc[g][3] + bv.w, 0.f);
      *(float4*)&fbuf[(size_t)(g0 + g) * 256 + col * 4] = o;
    }
  }
}

// ---------------------------------------------------------------------------
// K6: features = relu(f @ lin2_w + b2); x_lo = softmax(features)
// ---------------------------------------------------------------------------
__global__ __launch_bounds__(128) void k_head(
    const float* __restrict__ fbuf, const float* __restrict__ w2,
    const float* __restrict__ b2, float* __restrict__ out, int b0)
{
  __shared__ __align__(16) float fs[256];
  __shared__ float red[2];
  const int tid = threadIdx.x, lane = tid & 63, wv = tid >> 6;
  const int bl = blockIdx.x, b = b0 + bl;
  for (int i = tid; i < 256; i += 128) fs[i] = fbuf[(size_t)bl * 256 + i];
  __syncthreads();
  float acc = b2[tid];
  for (int k = 0; k < 256; k += 4) {
    float4 fq = *(const float4*)(fs + k);
    acc += fq.x * w2[(k + 0) * 128 + tid] + fq.y * w2[(k + 1) * 128 + tid]
         + fq.z * w2[(k + 2) * 128 + tid] + fq.w * w2[(k + 3) * 128 + tid];
  }
  float feat = fmaxf(acc, 0.0f);
  out[(size_t)(NB * 128) + (size_t)b * 128 + tid] = feat;
  float m = feat;
  for (int off = 32; off; off >>= 1) m = fmaxf(m, __shfl_xor(m, off));
  if (lane == 0) red[wv] = m;
  __syncthreads();
  m = fmaxf(red[0], red[1]);
  float e = expf(feat - m);
  float s = e;
  for (int off = 32; off; off >>= 1) s += __shfl_xor(s, off);
  __syncthreads();
  if (lane == 0) red[wv] = s;
  __syncthreads();
  s = red[0] + red[1];
  out[(size_t)b * 128 + tid] = e / s;
}

// ---------------------------------------------------------------------------
extern "C" void kernel_launch(void* const* d_in, const int* in_sizes, int n_in,
                              void* d_out, int out_size, void* d_ws, size_t ws_size,
                              hipStream_t stream) {
  const float* x    = (const float*)d_in[0];
  const float* adj  = (const float*)d_in[1];
  const float* wg1  = (const float*)d_in[2];
  const float* wsp1 = (const float*)d_in[3];
  const float* wg2  = (const float*)d_in[4];
  const float* wsp2 = (const float*)d_in[5];
  const float* l1w  = (const float*)d_in[6];
  const float* l1b  = (const float*)d_in[7];
  const float* l2w  = (const float*)d_in[8];
  const float* l2b  = (const float*)d_in[9];
  float* out = (float*)d_out;

  auto al = [](size_t v) { return (v + 255) & ~(size_t)255; };
  size_t oh1, ohp1, oadjp, oz, of;
  auto plan = [&](int g) -> size_t {
    size_t o = 0;
    oh1 = o;   o += al((size_t)g * NN0 * FD * 4);   // h1 (h2 overlay)
    ohp1 = o;  o += al((size_t)g * NN1 * FD * 4);
    oadjp = o; o += al((size_t)g * NN1 * 8);
    oz = o;    o += al((size_t)g * 8192 * 4);
    of = o;    o += al((size_t)g * FD * 4);
    return o;
  };
  int G = 2048;
  while (G > 64 && plan(G) > ws_size) G >>= 1;
  if (plan(G) > ws_size) return;

  char* wsb = (char*)d_ws;
  float* h1  = (float*)(wsb + oh1);
  float* hp1 = (float*)(wsb + ohp1);
  unsigned long long* adjp = (unsigned long long*)(wsb + oadjp);
  float* zbuf = (float*)(wsb + oz);
  float* fbuf = (float*)(wsb + of);

  const size_t LDS1 = (size_t)(12432 + 7168 + 448 + 112 + 112) * 4;   // 81,088 (2 blk/CU)
  const size_t LDS2 = (size_t)(NN0*FD + 448 + 112 + 112 + 56) * 4;    // 116,576
  const size_t LDS3 = (size_t)(NN1*FD + 57*64 + 112 + 64 + 64) * 4;   // 72,896 (2 blk/CU)
  const size_t LDS4 = (size_t)(NN1*FD + 112 + 64 + 64 + 32) * 4;      // 58,432

  for (int b0 = 0; b0 < NB; b0 += G) {
    k_stage1<<<G, 512, LDS1, stream>>>(x, adj, wg1, wsp1, h1, b0);
    k_pool1<<<G, 512, LDS2, stream>>>(h1, adj, hp1, adjp, zbuf, b0);
    k_stage2<<<G, 512, LDS3, stream>>>(hp1, adjp, wg2, wsp2, h1);
    k_pool2<<<G, 256, LDS4, stream>>>(h1, adjp, zbuf);
    k_lin1f<<<G / 8, 512, 0, stream>>>(zbuf, l1w, l1b, fbuf);
    k_head<<<G, 128, 0, stream>>>(fbuf, l2w, l2b, out, b0);
  }
}